// Round 5
// baseline (276.254 us; speedup 1.0000x reference)
//
#include <hip/hip_runtime.h>
#include <hip/hip_bf16.h>
#include <math.h>

#define SEQ 2048
#define HID 1024
#define NH 16
#define HD 64

using f32x4  = __attribute__((ext_vector_type(4))) float;
using bf16x8 = __attribute__((ext_vector_type(8))) short;

union U8 { unsigned int u[4]; bf16x8 v; short s[8]; };

__device__ __forceinline__ short f2bf(float f) {
  unsigned int x = __float_as_uint(f);
  unsigned int r = (x + 0x7fffu + ((x >> 16) & 1u)) >> 16;
  return (short)(r & 0xffffu);
}

__device__ __forceinline__ unsigned int pkbf(float a, float b) {
  return ((unsigned int)(unsigned short)f2bf(a)) |
         (((unsigned int)(unsigned short)f2bf(b)) << 16);
}

__device__ __forceinline__ float bf2f_lo(unsigned int u) {
  return __uint_as_float((u & 0xffffu) << 16);
}
__device__ __forceinline__ float bf2f_hi(unsigned int u) {
  return __uint_as_float(u & 0xffff0000u);
}

__device__ __forceinline__ float fast_exp2(float x) {
#if __has_builtin(__builtin_amdgcn_exp2f)
  return __builtin_amdgcn_exp2f(x);
#else
  return exp2f(x);
#endif
}

__device__ __forceinline__ float fast_rcp(float x) {
#if __has_builtin(__builtin_amdgcn_rcpf)
  return __builtin_amdgcn_rcpf(x);
#else
  return 1.0f / x;
#endif
}

__device__ __forceinline__ float gelu_f(float v) {
  float t = v * (1.5957691216057308f + 0.07135481283942279f * v * v);
  float e = fast_exp2(t * -1.4426950408889634f);
  return v * fast_rcp(1.0f + e);
}

__device__ __forceinline__ void async_cp16(const void* g, void* l) {
  __builtin_amdgcn_global_load_lds(
      (__attribute__((address_space(1))) void*)(g),
      (__attribute__((address_space(3))) void*)(l), 16, 0, 0);
}

// ------- fused: fp32->bf16 weight cvt (blocks 2048..14335) + LayerNorm0
// (blocks 0..2047). Independent work, one launch. -------
__global__ __launch_bounds__(256) void cvtln_kernel(
    const float* __restrict__ a, const float* __restrict__ b,
    const float* __restrict__ c, const float* __restrict__ d,
    short* __restrict__ oa, short* __restrict__ ob,
    short* __restrict__ oc, short* __restrict__ od,
    const float* __restrict__ x, const float* __restrict__ w,
    const float* __restrict__ bb, short* __restrict__ h0) {
  int tid = threadIdx.x;
  if (blockIdx.x < 2048) {
    int row = blockIdx.x;
    float4 v = ((const float4*)(x + (size_t)row * HID))[tid];
    float s  = v.x + v.y + v.z + v.w;
    float s2 = v.x*v.x + v.y*v.y + v.z*v.z + v.w*v.w;
#pragma unroll
    for (int o = 32; o >= 1; o >>= 1) {
      s  += __shfl_xor(s,  o);
      s2 += __shfl_xor(s2, o);
    }
    __shared__ float red[8];
    int wv = tid >> 6;
    if ((tid & 63) == 0) { red[wv] = s; red[4 + wv] = s2; }
    __syncthreads();
    float ts  = red[0] + red[1] + red[2] + red[3];
    float ts2 = red[4] + red[5] + red[6] + red[7];
    float mean = ts * (1.0f / HID);
    float var  = ts2 * (1.0f / HID) - mean * mean;
    float rs = rsqrtf(var + 1e-5f);
    float4 wv4 = ((const float4*)w)[tid];
    float4 bv4 = ((const float4*)bb)[tid];
    short4 o;
    o.x = f2bf((v.x - mean) * rs * wv4.x + bv4.x);
    o.y = f2bf((v.y - mean) * rs * wv4.y + bv4.y);
    o.z = f2bf((v.z - mean) * rs * wv4.z + bv4.z);
    o.w = f2bf((v.w - mean) * rs * wv4.w + bv4.w);
    ((short4*)(h0 + (size_t)row * HID))[tid] = o;
    return;
  }
  int i = (blockIdx.x - 2048) * 256 + tid;  // float4 index, 3145728 total
  const float* src; short* dst; int off;
  if (i < 786432)        { src = a; dst = oa; off = i; }
  else if (i < 1048576)  { src = b; dst = ob; off = i - 786432; }
  else if (i < 2097152)  { src = c; dst = oc; off = i - 1048576; }
  else                   { src = d; dst = od; off = i - 2097152; }
  float4 v = ((const float4*)src)[off];
  short4 o;
  o.x = f2bf(v.x); o.y = f2bf(v.y); o.z = f2bf(v.z); o.w = f2bf(v.w);
  ((short4*)dst)[off] = o;
}

// ---- Fused RoPE(q,k) + V-transpose, per (s0-block of 64, head) ----
__global__ __launch_bounds__(256) void ropev_kernel(const short* __restrict__ qkvb,
    const float* __restrict__ cosb, const float* __restrict__ sinb,
    short* __restrict__ Qh, short* __restrict__ Kh, short* __restrict__ Vt) {
  __shared__ short tile[64 * 72];
  int s0   = blockIdx.x * 64;
  int head = blockIdx.y;
  int tid  = threadIdx.x;
#pragma unroll
  for (int p = 0; p < 2; p++) {
    int seg = p * 256 + tid;
    int row = seg >> 3;
    int c8  = seg & 7;
    bf16x8 v = *(const bf16x8*)(qkvb + (size_t)(s0 + row) * 3072 + 2048 + head * 64 + c8 * 8);
    *(bf16x8*)(tile + row * 72 + c8 * 8) = v;
  }
  int sl = tid >> 3;
  int c  = tid & 7;
#pragma unroll
  for (int j = 0; j < 2; j++) {        // 0 = q, 1 = k
    float scale = (j == 0) ? 0.18033688011112043f : 1.0f;  // 0.125*log2(e)
    short* dstm = (j == 0) ? Qh : Kh;
#pragma unroll
    for (int half = 0; half < 2; half++) {
      int s = s0 + half * 32 + sl;
      uint4 uu = *(const uint4*)(qkvb + (size_t)s * 3072 + j * 1024 + head * 64 + c * 8);
      float4 cs = *(const float4*)(cosb + s * 32 + c * 4);
      float4 sn = *(const float4*)(sinb + s * 32 + c * 4);
      uint4 oo;
      {
        float a = bf2f_lo(uu.x), b = bf2f_hi(uu.x);
        oo.x = pkbf(scale * (a * cs.x - b * sn.x), scale * (a * sn.x + b * cs.x));
        a = bf2f_lo(uu.y); b = bf2f_hi(uu.y);
        oo.y = pkbf(scale * (a * cs.y - b * sn.y), scale * (a * sn.y + b * cs.y));
        a = bf2f_lo(uu.z); b = bf2f_hi(uu.z);
        oo.z = pkbf(scale * (a * cs.z - b * sn.z), scale * (a * sn.z + b * cs.z));
        a = bf2f_lo(uu.w); b = bf2f_hi(uu.w);
        oo.w = pkbf(scale * (a * cs.w - b * sn.w), scale * (a * sn.w + b * cs.w));
      }
      *(uint4*)(dstm + ((size_t)head * SEQ + s) * HD + c * 8) = oo;
    }
  }
  __syncthreads();
#pragma unroll
  for (int p = 0; p < 2; p++) {
    int seg = p * 256 + tid;
    int d   = seg >> 3;
    int sc  = seg & 7;
    U8 o;
#pragma unroll
    for (int jj = 0; jj < 8; jj++) o.s[jj] = tile[(sc * 8 + jj) * 72 + d];
    *(bf16x8*)(Vt + ((size_t)head * HD + d) * SEQ + s0 + sc * 8) = o.v;
  }
}

// ---------------- GEMM: C(MxN) = A(MxK) * B(NxK)^T, bf16 MFMA, BK=64 -------
// LDS pitch 64 shorts, slot = chunk ^ (row&7) (bank-even, verified symbolically).
// R10-proven: 64 KB ping-pong + counted vmcnt(8) + raw s_barrier. All our
// GEMM grids cap at <=2 blocks/CU, and 64 KB LDS still allows 2 blocks/CU,
// so the dbuf costs no residency. vmcnt(0) only on the last K-step.
// EPI 2: gelu bf16, EPI 3: bias bf16, EPI 5: split-K bf16 partial
template <int EPI>
__global__ __launch_bounds__(256) void gemm_bt_kernel(
    const short* __restrict__ A, const short* __restrict__ B,
    const float* __restrict__ bias, const float* __restrict__ resid,
    void* __restrict__ outp, int M, int N, int Klen, int Kstride) {
  __shared__ __attribute__((aligned(16))) short Alds[2 * 128 * 64];
  __shared__ __attribute__((aligned(16))) short Blds[2 * 128 * 64];
  int tid = threadIdx.x;
  int w    = tid >> 6;
  int lane = tid & 63;
  int lcol  = lane & 15;
  int lhalf = lane >> 4;
  int m0 = blockIdx.y * 128;
  int n0 = blockIdx.x * 128;
  int z  = blockIdx.z;
  int wm = (w & 1) * 64;
  int wn = (w >> 1) * 64;

  // staging: 4 cp16 rounds per buffer; global chunk swizzled by row&7
  const short* apt[4];
  const short* bpt[4];
#pragma unroll
  for (int p = 0; p < 4; p++) {
    int seg = p * 256 + tid;
    int row = seg >> 3;
    int c   = (seg & 7) ^ (row & 7);
    apt[p] = A + (size_t)z * Klen + (size_t)(m0 + row) * Kstride + c * 8;
    bpt[p] = B + (size_t)z * Klen + (size_t)(n0 + row) * Kstride + c * 8;
  }

  f32x4 acc[4][4];
#pragma unroll
  for (int i = 0; i < 4; i++)
#pragma unroll
    for (int j = 0; j < 4; j++) acc[i][j] = (f32x4){0.f, 0.f, 0.f, 0.f};

  int nk = Klen >> 6;
  // prologue: stage K-tile 0 into buffer 0
#pragma unroll
  for (int p = 0; p < 4; p++) {
    async_cp16(apt[p], Alds + p * 2048 + w * 512);  apt[p] += 64;
    async_cp16(bpt[p], Blds + p * 2048 + w * 512);  bpt[p] += 64;
  }
  for (int kt = 0; kt < nk; ++kt) {
    int cur = kt & 1;
    const short* Ab = Alds + cur * 8192;
    const short* Bb = Blds + cur * 8192;
    if (kt + 1 < nk) {
      int nb = (cur ^ 1) * 8192;
#pragma unroll
      for (int p = 0; p < 4; p++) {
        async_cp16(apt[p], Alds + nb + p * 2048 + w * 512);  apt[p] += 64;
        async_cp16(bpt[p], Blds + nb + p * 2048 + w * 512);  bpt[p] += 64;
      }
      asm volatile("s_waitcnt vmcnt(8)" ::: "memory");  // tile kt landed
    } else {
      asm volatile("s_waitcnt vmcnt(0)" ::: "memory");
    }
    __builtin_amdgcn_s_barrier();
    __builtin_amdgcn_sched_barrier(0);
#pragma unroll
    for (int kc = 0; kc < 2; kc++) {
      bf16x8 af[4], bfr[4];
#pragma unroll
      for (int i = 0; i < 4; i++) {
        int row = wm + i * 16 + lcol;
        af[i] = *(const bf16x8*)(Ab + row * 64 + (((kc * 4 + lhalf) ^ (row & 7)) * 8));
      }
#pragma unroll
      for (int j = 0; j < 4; j++) {
        int row = wn + j * 16 + lcol;
        bfr[j] = *(const bf16x8*)(Bb + row * 64 + (((kc * 4 + lhalf) ^ (row & 7)) * 8));
      }
#pragma unroll
      for (int i = 0; i < 4; i++)
#pragma unroll
        for (int j = 0; j < 4; j++)
          acc[i][j] = __builtin_amdgcn_mfma_f32_16x16x32_bf16(af[i], bfr[j], acc[i][j], 0, 0, 0);
    }
    __builtin_amdgcn_s_barrier();
    __builtin_amdgcn_sched_barrier(0);
  }

#pragma unroll
  for (int i = 0; i < 4; i++) {
#pragma unroll
    for (int j = 0; j < 4; j++) {
#pragma unroll
      for (int r = 0; r < 4; r++) {
        int row = m0 + wm + i * 16 + lhalf * 4 + r;
        int col = n0 + wn + j * 16 + lcol;
        float v = acc[i][j][r];
        if (EPI != 5) v += bias[col];
        if (EPI == 2) {
          v = gelu_f(v);
          ((short*)outp)[(size_t)row * N + col] = f2bf(v);
        } else if (EPI == 3) {
          ((short*)outp)[(size_t)row * N + col] = f2bf(v);
        } else {  // EPI 5: bf16 partial
          ((short*)outp)[(size_t)z * M * N + (size_t)row * N + col] = f2bf(v);
        }
      }
    }
  }
}

// ---- Attention R13: 4 waves x 32 q-rows/wave (2 q-tiles), z-split 4 ----
// R12 A/B proved residency is not the limiter (6blk x 4w and 4blk x 8w both
// 42 us): the kernel is LDS-read-BW bound (every wave reads the full 16 KB
// K+V tile per t0 step; total ~1.6 GB ~ 30 us floor at measured b128 rate).
// Fix: each wave now owns TWO q-column-tiles (qrow w*32 and w*32+16) so the
// same K/V LDS reads feed 2x the MFMA work -> K/V read traffic per unit
// work halves. kf/ke/vf fragments shared across both q-tiles.
__global__ __launch_bounds__(256) void attn_kernel(
    const short* __restrict__ Qh, const short* __restrict__ Kh,
    const short* __restrict__ Vt, const int* __restrict__ offs,
    short* __restrict__ Opart, float* __restrict__ Lpart) {
  __shared__ __attribute__((aligned(16))) short Klds[64 * 64];
  __shared__ __attribute__((aligned(16))) short Vlds[64 * 64];
  __shared__ __attribute__((aligned(16))) unsigned int Plds[4][2][16 * 34];
  int head = blockIdx.y;
  int q0   = blockIdx.x * 128;
  int z    = blockIdx.z;
  int tid  = threadIdx.x;
  int w    = tid >> 6;      // 0..3
  int lane = tid & 63;
  int lcol = lane & 15;
  int h    = lane >> 4;
  int s7   = lcol & 7;
  int o1 = offs[1], o2 = offs[2], o3 = offs[3];

  int qrowA = q0 + w * 32 + lcol;
  int qrowB = qrowA + 16;
  const short* qbA = Qh + ((size_t)head * SEQ + qrowA) * HD;
  const short* qbB = Qh + ((size_t)head * SEQ + qrowB) * HD;
  bf16x8 qfA0 = *(const bf16x8*)(qbA + h * 8);
  bf16x8 qfA1 = *(const bf16x8*)(qbA + 32 + h * 8);
  bf16x8 qfB0 = *(const bf16x8*)(qbB + h * 8);
  bf16x8 qfB1 = *(const bf16x8*)(qbB + 32 + h * 8);
  int sqA = (qrowA >= o1) + (qrowA >= o2) + (qrowA >= o3);
  int sqB = (qrowB >= o1) + (qrowB >= o2) + (qrowB >= o3);
  U8 qeA, qeB;
  qeA.u[0] = 0; qeA.u[1] = 0; qeA.u[2] = 0; qeA.u[3] = 0;
  qeB.u[0] = 0; qeB.u[1] = 0; qeB.u[2] = 0; qeB.u[3] = 0;
  if (h == 0) { qeA.s[sqA] = (short)0x3FB9; qeB.s[sqB] = (short)0x3FB9; }  // bf16(log2e)

  bf16x8 ones;
#pragma unroll
  for (int i = 0; i < 8; i++) ones[i] = 0x3F80;

  int kb0 = lcol * 64 + ((h ^ s7) * 8);
  int kb1 = lcol * 64 + (((4 + h) ^ s7) * 8);
  int vb0 = kb0, vb1 = kb1;
  int pwb = lcol * 34 + h * 2;
  int prb = lcol * 34 + h * 4;

  int tbeg = z * 512;
  const short* kp0; const short* kp1; const short* vp0; const short* vp1;
  {
    int seg = tid, row = seg >> 3, g = (seg & 7) ^ (row & 7);
    kp0 = Kh + ((size_t)head * SEQ + tbeg + row) * HD + g * 8;
    vp0 = Vt + ((size_t)head * HD + row) * SEQ + tbeg + g * 8;
    seg = 256 + tid; row = seg >> 3; g = (seg & 7) ^ (row & 7);
    kp1 = Kh + ((size_t)head * SEQ + tbeg + row) * HD + g * 8;
    vp1 = Vt + ((size_t)head * HD + row) * SEQ + tbeg + g * 8;
  }

  f32x4 oA[4], oB[4];
#pragma unroll
  for (int nt = 0; nt < 4; nt++) {
    oA[nt] = (f32x4){0.f, 0.f, 0.f, 0.f};
    oB[nt] = (f32x4){0.f, 0.f, 0.f, 0.f};
  }
  f32x4 lA = (f32x4){0.f, 0.f, 0.f, 0.f};
  f32x4 lB = (f32x4){0.f, 0.f, 0.f, 0.f};

  for (int t0 = 0; t0 < 512; t0 += 64) {
    async_cp16(kp0, Klds + w * 512);          kp0 += 64 * HD;
    async_cp16(kp1, Klds + 2048 + w * 512);   kp1 += 64 * HD;
    async_cp16(vp0, Vlds + w * 512);          vp0 += 64;
    async_cp16(vp1, Vlds + 2048 + w * 512);   vp1 += 64;
    __syncthreads();

#pragma unroll
    for (int n = 0; n < 4; n++) {
      bf16x8 kf0 = *(const bf16x8*)(Klds + n * 1024 + kb0);
      bf16x8 kf1 = *(const bf16x8*)(Klds + n * 1024 + kb1);
      int key = tbeg + t0 + n * 16 + lcol;
      int sk = (key >= o1) + (key >= o2) + (key >= o3);
      U8 ke;
      ke.u[0] = (h == 0) ? ((sk == 0) ? 0x00003F80u : (sk == 1) ? 0x3F800000u : 0u) : 0u;
      ke.u[1] = (h == 0) ? ((sk == 2) ? 0x00003F80u : (sk == 3) ? 0x3F800000u : 0u) : 0u;
      ke.u[2] = 0; ke.u[3] = 0;

      f32x4 sA = (f32x4){0.f, 0.f, 0.f, 0.f};
      sA = __builtin_amdgcn_mfma_f32_16x16x32_bf16(kf0, qfA0, sA, 0, 0, 0);
      sA = __builtin_amdgcn_mfma_f32_16x16x32_bf16(kf1, qfA1, sA, 0, 0, 0);
      sA = __builtin_amdgcn_mfma_f32_16x16x32_bf16(ke.v, qeA.v, sA, 0, 0, 0);
      f32x4 sB = (f32x4){0.f, 0.f, 0.f, 0.f};
      sB = __builtin_amdgcn_mfma_f32_16x16x32_bf16(kf0, qfB0, sB, 0, 0, 0);
      sB = __builtin_amdgcn_mfma_f32_16x16x32_bf16(kf1, qfB1, sB, 0, 0, 0);
      sB = __builtin_amdgcn_mfma_f32_16x16x32_bf16(ke.v, qeB.v, sB, 0, 0, 0);

      uint2 pw;
      pw.x = __builtin_amdgcn_perm(__float_as_uint(fast_exp2(sA[1])),
                                   __float_as_uint(fast_exp2(sA[0])), 0x07060302);
      pw.y = __builtin_amdgcn_perm(__float_as_uint(fast_exp2(sA[3])),
                                   __float_as_uint(fast_exp2(sA[2])), 0x07060302);
      *(uint2*)&Plds[w][0][pwb + n * 8] = pw;
      pw.x = __builtin_amdgcn_perm(__float_as_uint(fast_exp2(sB[1])),
                                   __float_as_uint(fast_exp2(sB[0])), 0x07060302);
      pw.y = __builtin_amdgcn_perm(__float_as_uint(fast_exp2(sB[3])),
                                   __float_as_uint(fast_exp2(sB[2])), 0x07060302);
      *(uint2*)&Plds[w][1][pwb + n * 8] = pw;
    }

#pragma unroll
    for (int kc = 0; kc < 2; kc++) {
      uint2 a = *(const uint2*)&Plds[w][0][prb + kc * 16];
      uint2 b = *(const uint2*)&Plds[w][0][prb + kc * 16 + 2];
      U8 puA;
      puA.u[0] = a.x; puA.u[1] = a.y; puA.u[2] = b.x; puA.u[3] = b.y;
      a = *(const uint2*)&Plds[w][1][prb + kc * 16];
      b = *(const uint2*)&Plds[w][1][prb + kc * 16 + 2];
      U8 puB;
      puB.u[0] = a.x; puB.u[1] = a.y; puB.u[2] = b.x; puB.u[3] = b.y;
      int vb = kc ? vb1 : vb0;
#pragma unroll
      for (int nt = 0; nt < 4; nt++) {
        bf16x8 vf = *(const bf16x8*)(Vlds + nt * 1024 + vb);
        oA[nt] = __builtin_amdgcn_mfma_f32_16x16x32_bf16(vf, puA.v, oA[nt], 0, 0, 0);
        oB[nt] = __builtin_amdgcn_mfma_f32_16x16x32_bf16(vf, puB.v, oB[nt], 0, 0, 0);
      }
      lA = __builtin_amdgcn_mfma_f32_16x16x32_bf16(ones, puA.v, lA, 0, 0, 0);
      lB = __builtin_amdgcn_mfma_f32_16x16x32_bf16(ones, puB.v, lB, 0, 0, 0);
    }
    __syncthreads();
  }

  short* opA = Opart + ((size_t)z * SEQ + qrowA) * HID + head * HD + h * 4;
  short* opB = Opart + ((size_t)z * SEQ + qrowB) * HID + head * HD + h * 4;
#pragma unroll
  for (int nt = 0; nt < 4; nt++) {
    uint2 ua;
    ua.x = pkbf(oA[nt][0], oA[nt][1]);
    ua.y = pkbf(oA[nt][2], oA[nt][3]);
    *(uint2*)(opA + nt * 16) = ua;
    ua.x = pkbf(oB[nt][0], oB[nt][1]);
    ua.y = pkbf(oB[nt][2], oB[nt][3]);
    *(uint2*)(opB + nt * 16) = ua;
  }
  if (lane < 16) {
    Lpart[((size_t)z * NH + head) * SEQ + qrowA] = lA[0];
    Lpart[((size_t)z * NH + head) * SEQ + qrowB] = lB[0];
  }
}

// ---- merge 4 bf16 z-partials, normalize by sum(l), out bf16 ----
__global__ __launch_bounds__(256) void attn_merge_kernel(
    const short* __restrict__ Opart, const float* __restrict__ Lpart,
    short* __restrict__ attn) {
  int i = blockIdx.x * blockDim.x + threadIdx.x;
  int col4 = i & 255;
  int row  = i >> 8;
  int head = col4 >> 4;
  float acc0 = 0.f, acc1 = 0.f, acc2 = 0.f, acc3 = 0.f, l = 0.f;
#pragma unroll
  for (int zz = 0; zz < 4; zz++) {
    uint2 p = ((const uint2*)(Opart + (size_t)zz * SEQ * HID))[i];
    acc0 += bf2f_lo(p.x); acc1 += bf2f_hi(p.x);
    acc2 += bf2f_lo(p.y); acc3 += bf2f_hi(p.y);
    l += Lpart[((size_t)zz * NH + head) * SEQ + row];
  }
  float rl = fast_rcp(l);
  uint2 o;
  o.x = pkbf(acc0 * rl, acc1 * rl);
  o.y = pkbf(acc2 * rl, acc3 * rl);
  ((uint2*)attn)[i] = o;
}

// ------- split-K bf16-partial merge + bias + residual + LayerNorm -------
__global__ __launch_bounds__(256) void merge_ln_kernel(
    const short* __restrict__ part, const float* __restrict__ bias,
    const float* __restrict__ resid, const float* __restrict__ w,
    const float* __restrict__ b, float* __restrict__ x1, short* __restrict__ h1) {
  int row = blockIdx.x;
  int tid = threadIdx.x;
  size_t idx = (size_t)row * HID / 4 + tid;
  float4 v = {0.f, 0.f, 0.f, 0.f};
#pragma unroll
  for (int z = 0; z < 4; z++) {
    uint2 p = ((const uint2*)(part + (size_t)z * SEQ * HID))[idx];
    v.x += bf2f_lo(p.x); v.y += bf2f_hi(p.x);
    v.z += bf2f_lo(p.y); v.w += bf2f_hi(p.y);
  }
  float4 bi = ((const float4*)bias)[tid];
  float4 rs4 = ((const float4*)(resid + (size_t)row * HID))[tid];
  v.x += bi.x + rs4.x; v.y += bi.y + rs4.y; v.z += bi.z + rs4.z; v.w += bi.w + rs4.w;
  ((float4*)(x1 + (size_t)row * HID))[tid] = v;
  float s  = v.x + v.y + v.z + v.w;
  float s2 = v.x*v.x + v.y*v.y + v.z*v.z + v.w*v.w;
#pragma unroll
  for (int o = 32; o >= 1; o >>= 1) {
    s  += __shfl_xor(s,  o);
    s2 += __shfl_xor(s2, o);
  }
  __shared__ float red[8];
  int wv = tid >> 6;
  if ((tid & 63) == 0) { red[wv] = s; red[4 + wv] = s2; }
  __syncthreads();
  float ts  = red[0] + red[1] + red[2] + red[3];
  float ts2 = red[4] + red[5] + red[6] + red[7];
  float mean = ts * (1.0f / HID);
  float var  = ts2 * (1.0f / HID) - mean * mean;
  float rsq = rsqrtf(var + 1e-5f);
  float4 wv4 = ((const float4*)w)[tid];
  float4 bv4 = ((const float4*)b)[tid];
  short4 o;
  o.x = f2bf((v.x - mean) * rsq * wv4.x + bv4.x);
  o.y = f2bf((v.y - mean) * rsq * wv4.y + bv4.y);
  o.z = f2bf((v.z - mean) * rsq * wv4.z + bv4.z);
  o.w = f2bf((v.w - mean) * rsq * wv4.w + bv4.w);
  ((short4*)(h1 + (size_t)row * HID))[tid] = o;
}

// ------- split-K bf16-partial merge + bias + residual -> fp32 out -------
__global__ __launch_bounds__(256) void merge_bias_kernel(
    const short* __restrict__ part, const float* __restrict__ bias,
    const float* __restrict__ resid, float* __restrict__ out) {
  int i = blockIdx.x * blockDim.x + threadIdx.x;
  int col4 = i & 255;
  float4 v = {0.f, 0.f, 0.f, 0.f};
#pragma unroll
  for (int z = 0; z < 4; z++) {
    uint2 p = ((const uint2*)(part + (size_t)z * SEQ * HID))[i];
    v.x += bf2f_lo(p.x); v.y += bf2f_hi(p.x);
    v.z += bf2f_lo(p.y); v.w += bf2f_hi(p.y);
  }
  float4 bi = ((const float4*)bias)[col4];
  float4 rs = ((const float4*)resid)[i];
  float4 o;
  o.x = v.x + bi.x + rs.x;
  o.y = v.y + bi.y + rs.y;
  o.z = v.z + bi.z + rs.z;
  o.w = v.w + bi.w + rs.w;
  ((float4*)out)[i] = o;
}

extern "C" void kernel_launch(void* const* d_in, const int* in_sizes, int n_in,
                              void* d_out, int out_size, void* d_ws, size_t ws_size,
                              hipStream_t stream) {
  const float* x      = (const float*)d_in[0];
  const float* ropec  = (const float*)d_in[1];
  const float* ropes  = (const float*)d_in[2];
  const float* n0w    = (const float*)d_in[3];
  const float* n0b    = (const float*)d_in[4];
  const float* n1w    = (const float*)d_in[5];
  const float* n1b    = (const float*)d_in[6];
  const float* wqkv_w = (const float*)d_in[7];
  const float* wqkv_b = (const float*)d_in[8];
  const float* wo_w   = (const float*)d_in[9];
  const float* wo_b   = (const float*)d_in[10];
  const float* up_w   = (const float*)d_in[11];
  const float* up_b   = (const float*)d_in[12];
  const float* down_w = (const float*)d_in[13];
  const float* down_b = (const float*)d_in[14];
  const int*   offs   = (const int*)d_in[15];
  float* out = (float*)d_out;

  char* base = (char*)d_ws;
  // ---- static layout, lifetime-aliased (peak ~88.6 MB) ----
  short* wqkv_bf = (short*)(base + 0);            //  6.3 MB, whole run
  short* wo_bf   = (short*)(base + 6291456);      //  2.1 MB, whole run
  short* up_bf   = (short*)(base + 8388608);      //  8.4 MB, whole run
  short* down_bf = (short*)(base + 16777216);     //  8.4 MB, whole run
  short* h0      = (short*)(base + 25165824);     //  4.2 MB, dead after qkv gemm
  short* qkv_bf  = (short*)(base + 29360128);     // 12.6 MB, dead after ropev
  short* Qh      = (short*)(base + 41943040);     //  4.2 MB, dead after attn
  short* Kh      = (short*)(base + 46137344);     //  4.2 MB, dead after attn
  short* Vt      = (short*)(base + 50331648);     //  4.2 MB, dead after attn
  short* Opart   = (short*)(base + 54525952);     // 16.8 MB, dead after attn_merge
  float* Lpart   = (float*)(base + 71303168);     //  0.5 MB
  short* attn    = (short*)(base + 71827456);     //  4.2 MB, dead after wo gemm
  float* x1      = (float*)(base + 76021760);     //  8.4 MB, live to end
  short* h1      = (short*)(base + 84410368);     //  4.2 MB, dead after up gemm
  short* wopart  = (short*)(base + 25165824);     // 16.8 MB -> 41.9 MB (h0..Vt dead)
  short* u       = (short*)(base + 25165824);     // 16.8 MB -> 41.9 MB
  short* dnpart  = (short*)(base + 41943040);     // 16.8 MB -> 58.7 MB (Qh..Opart dead)

  cvtln_kernel<<<14336, 256, 0, stream>>>(wqkv_w, wo_w, up_w, down_w,
                                          wqkv_bf, wo_bf, up_bf, down_bf,
                                          x, n0w, n0b, h0);
  gemm_bt_kernel<3><<<dim3(24, 16), 256, 0, stream>>>(h0, wqkv_bf, wqkv_b, nullptr,
                                                      qkv_bf, 2048, 3072, 1024, 1024);
  ropev_kernel<<<dim3(32, 16), 256, 0, stream>>>(qkv_bf, ropec, ropes, Qh, Kh, Vt);
  attn_kernel<<<dim3(16, 16, 4), 256, 0, stream>>>(Qh, Kh, Vt, offs, Opart, Lpart);
  attn_merge_kernel<<<2048, 256, 0, stream>>>(Opart, Lpart, attn);
  gemm_bt_kernel<5><<<dim3(8, 16, 4), 256, 0, stream>>>(attn, wo_bf, nullptr, nullptr,
                                                        wopart, 2048, 1024, 256, 1024);
  merge_ln_kernel<<<2048, 256, 0, stream>>>(wopart, wo_b, x, n1w, n1b, x1, h1);
  gemm_bt_kernel<2><<<dim3(32, 16), 256, 0, stream>>>(h1, up_bf, up_b, nullptr,
                                                      u, 2048, 4096, 1024, 1024);
  gemm_bt_kernel<5><<<dim3(8, 16, 4), 256, 0, stream>>>(u, down_bf, nullptr, nullptr,
                                                        dnpart, 2048, 1024, 1024, 4096);
  merge_bias_kernel<<<2048, 256, 0, stream>>>(dnpart, down_b, x1, out);
}

// Round 6
// 264.321 us; speedup vs baseline: 1.0451x; 1.0451x over previous
//
#include <hip/hip_runtime.h>
#include <hip/hip_bf16.h>
#include <math.h>

#define SEQ 2048
#define HID 1024
#define NH 16
#define HD 64

using f32x4  = __attribute__((ext_vector_type(4))) float;
using bf16x8 = __attribute__((ext_vector_type(8))) short;

union U8 { unsigned int u[4]; bf16x8 v; short s[8]; };

__device__ __forceinline__ short f2bf(float f) {
  unsigned int x = __float_as_uint(f);
  unsigned int r = (x + 0x7fffu + ((x >> 16) & 1u)) >> 16;
  return (short)(r & 0xffffu);
}

__device__ __forceinline__ unsigned int pkbf(float a, float b) {
  return ((unsigned int)(unsigned short)f2bf(a)) |
         (((unsigned int)(unsigned short)f2bf(b)) << 16);
}

__device__ __forceinline__ float bf2f_lo(unsigned int u) {
  return __uint_as_float((u & 0xffffu) << 16);
}
__device__ __forceinline__ float bf2f_hi(unsigned int u) {
  return __uint_as_float(u & 0xffff0000u);
}

__device__ __forceinline__ float fast_exp2(float x) {
#if __has_builtin(__builtin_amdgcn_exp2f)
  return __builtin_amdgcn_exp2f(x);
#else
  return exp2f(x);
#endif
}

__device__ __forceinline__ float fast_rcp(float x) {
#if __has_builtin(__builtin_amdgcn_rcpf)
  return __builtin_amdgcn_rcpf(x);
#else
  return 1.0f / x;
#endif
}

__device__ __forceinline__ float gelu_f(float v) {
  float t = v * (1.5957691216057308f + 0.07135481283942279f * v * v);
  float e = fast_exp2(t * -1.4426950408889634f);
  return v * fast_rcp(1.0f + e);
}

__device__ __forceinline__ void async_cp16(const void* g, void* l) {
  __builtin_amdgcn_global_load_lds(
      (__attribute__((address_space(1))) void*)(g),
      (__attribute__((address_space(3))) void*)(l), 16, 0, 0);
}

// ------- fused: fp32->bf16 weight cvt (blocks 2048..14335) + LayerNorm0
// (blocks 0..2047). Independent work, one launch. -------
__global__ __launch_bounds__(256) void cvtln_kernel(
    const float* __restrict__ a, const float* __restrict__ b,
    const float* __restrict__ c, const float* __restrict__ d,
    short* __restrict__ oa, short* __restrict__ ob,
    short* __restrict__ oc, short* __restrict__ od,
    const float* __restrict__ x, const float* __restrict__ w,
    const float* __restrict__ bb, short* __restrict__ h0) {
  int tid = threadIdx.x;
  if (blockIdx.x < 2048) {
    int row = blockIdx.x;
    float4 v = ((const float4*)(x + (size_t)row * HID))[tid];
    float s  = v.x + v.y + v.z + v.w;
    float s2 = v.x*v.x + v.y*v.y + v.z*v.z + v.w*v.w;
#pragma unroll
    for (int o = 32; o >= 1; o >>= 1) {
      s  += __shfl_xor(s,  o);
      s2 += __shfl_xor(s2, o);
    }
    __shared__ float red[8];
    int wv = tid >> 6;
    if ((tid & 63) == 0) { red[wv] = s; red[4 + wv] = s2; }
    __syncthreads();
    float ts  = red[0] + red[1] + red[2] + red[3];
    float ts2 = red[4] + red[5] + red[6] + red[7];
    float mean = ts * (1.0f / HID);
    float var  = ts2 * (1.0f / HID) - mean * mean;
    float rs = rsqrtf(var + 1e-5f);
    float4 wv4 = ((const float4*)w)[tid];
    float4 bv4 = ((const float4*)bb)[tid];
    short4 o;
    o.x = f2bf((v.x - mean) * rs * wv4.x + bv4.x);
    o.y = f2bf((v.y - mean) * rs * wv4.y + bv4.y);
    o.z = f2bf((v.z - mean) * rs * wv4.z + bv4.z);
    o.w = f2bf((v.w - mean) * rs * wv4.w + bv4.w);
    ((short4*)(h0 + (size_t)row * HID))[tid] = o;
    return;
  }
  int i = (blockIdx.x - 2048) * 256 + tid;  // float4 index, 3145728 total
  const float* src; short* dst; int off;
  if (i < 786432)        { src = a; dst = oa; off = i; }
  else if (i < 1048576)  { src = b; dst = ob; off = i - 786432; }
  else if (i < 2097152)  { src = c; dst = oc; off = i - 1048576; }
  else                   { src = d; dst = od; off = i - 2097152; }
  float4 v = ((const float4*)src)[off];
  short4 o;
  o.x = f2bf(v.x); o.y = f2bf(v.y); o.z = f2bf(v.z); o.w = f2bf(v.w);
  ((short4*)dst)[off] = o;
}

// ---- Fused RoPE(q,k) + V-transpose, per (s0-block of 64, head) ----
__global__ __launch_bounds__(256) void ropev_kernel(const short* __restrict__ qkvb,
    const float* __restrict__ cosb, const float* __restrict__ sinb,
    short* __restrict__ Qh, short* __restrict__ Kh, short* __restrict__ Vt) {
  __shared__ short tile[64 * 72];
  int s0   = blockIdx.x * 64;
  int head = blockIdx.y;
  int tid  = threadIdx.x;
#pragma unroll
  for (int p = 0; p < 2; p++) {
    int seg = p * 256 + tid;
    int row = seg >> 3;
    int c8  = seg & 7;
    bf16x8 v = *(const bf16x8*)(qkvb + (size_t)(s0 + row) * 3072 + 2048 + head * 64 + c8 * 8);
    *(bf16x8*)(tile + row * 72 + c8 * 8) = v;
  }
  int sl = tid >> 3;
  int c  = tid & 7;
#pragma unroll
  for (int j = 0; j < 2; j++) {        // 0 = q, 1 = k
    float scale = (j == 0) ? 0.18033688011112043f : 1.0f;  // 0.125*log2(e)
    short* dstm = (j == 0) ? Qh : Kh;
#pragma unroll
    for (int half = 0; half < 2; half++) {
      int s = s0 + half * 32 + sl;
      uint4 uu = *(const uint4*)(qkvb + (size_t)s * 3072 + j * 1024 + head * 64 + c * 8);
      float4 cs = *(const float4*)(cosb + s * 32 + c * 4);
      float4 sn = *(const float4*)(sinb + s * 32 + c * 4);
      uint4 oo;
      {
        float a = bf2f_lo(uu.x), b = bf2f_hi(uu.x);
        oo.x = pkbf(scale * (a * cs.x - b * sn.x), scale * (a * sn.x + b * cs.x));
        a = bf2f_lo(uu.y); b = bf2f_hi(uu.y);
        oo.y = pkbf(scale * (a * cs.y - b * sn.y), scale * (a * sn.y + b * cs.y));
        a = bf2f_lo(uu.z); b = bf2f_hi(uu.z);
        oo.z = pkbf(scale * (a * cs.z - b * sn.z), scale * (a * sn.z + b * cs.z));
        a = bf2f_lo(uu.w); b = bf2f_hi(uu.w);
        oo.w = pkbf(scale * (a * cs.w - b * sn.w), scale * (a * sn.w + b * cs.w));
      }
      *(uint4*)(dstm + ((size_t)head * SEQ + s) * HD + c * 8) = oo;
    }
  }
  __syncthreads();
#pragma unroll
  for (int p = 0; p < 2; p++) {
    int seg = p * 256 + tid;
    int d   = seg >> 3;
    int sc  = seg & 7;
    U8 o;
#pragma unroll
    for (int jj = 0; jj < 8; jj++) o.s[jj] = tile[(sc * 8 + jj) * 72 + d];
    *(bf16x8*)(Vt + ((size_t)head * HD + d) * SEQ + s0 + sc * 8) = o.v;
  }
}

// ---------------- GEMM: C(MxN) = A(MxK) * B(NxK)^T, bf16 MFMA, BK=64 -------
// LDS pitch 64 shorts, slot = chunk ^ (row&7) (bank-even, verified symbolically).
// R10-proven: 64 KB ping-pong + counted vmcnt(8) + raw s_barrier. All our
// GEMM grids cap at <=2 blocks/CU, and 64 KB LDS still allows 2 blocks/CU,
// so the dbuf costs no residency. vmcnt(0) only on the last K-step.
// EPI 2: gelu bf16, EPI 3: bias bf16, EPI 5: split-K bf16 partial
template <int EPI>
__global__ __launch_bounds__(256) void gemm_bt_kernel(
    const short* __restrict__ A, const short* __restrict__ B,
    const float* __restrict__ bias, const float* __restrict__ resid,
    void* __restrict__ outp, int M, int N, int Klen, int Kstride) {
  __shared__ __attribute__((aligned(16))) short Alds[2 * 128 * 64];
  __shared__ __attribute__((aligned(16))) short Blds[2 * 128 * 64];
  int tid = threadIdx.x;
  int w    = tid >> 6;
  int lane = tid & 63;
  int lcol  = lane & 15;
  int lhalf = lane >> 4;
  int m0 = blockIdx.y * 128;
  int n0 = blockIdx.x * 128;
  int z  = blockIdx.z;
  int wm = (w & 1) * 64;
  int wn = (w >> 1) * 64;

  // staging: 4 cp16 rounds per buffer; global chunk swizzled by row&7
  const short* apt[4];
  const short* bpt[4];
#pragma unroll
  for (int p = 0; p < 4; p++) {
    int seg = p * 256 + tid;
    int row = seg >> 3;
    int c   = (seg & 7) ^ (row & 7);
    apt[p] = A + (size_t)z * Klen + (size_t)(m0 + row) * Kstride + c * 8;
    bpt[p] = B + (size_t)z * Klen + (size_t)(n0 + row) * Kstride + c * 8;
  }

  f32x4 acc[4][4];
#pragma unroll
  for (int i = 0; i < 4; i++)
#pragma unroll
    for (int j = 0; j < 4; j++) acc[i][j] = (f32x4){0.f, 0.f, 0.f, 0.f};

  int nk = Klen >> 6;
  // prologue: stage K-tile 0 into buffer 0
#pragma unroll
  for (int p = 0; p < 4; p++) {
    async_cp16(apt[p], Alds + p * 2048 + w * 512);  apt[p] += 64;
    async_cp16(bpt[p], Blds + p * 2048 + w * 512);  bpt[p] += 64;
  }
  for (int kt = 0; kt < nk; ++kt) {
    int cur = kt & 1;
    const short* Ab = Alds + cur * 8192;
    const short* Bb = Blds + cur * 8192;
    if (kt + 1 < nk) {
      int nb = (cur ^ 1) * 8192;
#pragma unroll
      for (int p = 0; p < 4; p++) {
        async_cp16(apt[p], Alds + nb + p * 2048 + w * 512);  apt[p] += 64;
        async_cp16(bpt[p], Blds + nb + p * 2048 + w * 512);  bpt[p] += 64;
      }
      asm volatile("s_waitcnt vmcnt(8)" ::: "memory");  // tile kt landed
    } else {
      asm volatile("s_waitcnt vmcnt(0)" ::: "memory");
    }
    __builtin_amdgcn_s_barrier();
    __builtin_amdgcn_sched_barrier(0);
#pragma unroll
    for (int kc = 0; kc < 2; kc++) {
      bf16x8 af[4], bfr[4];
#pragma unroll
      for (int i = 0; i < 4; i++) {
        int row = wm + i * 16 + lcol;
        af[i] = *(const bf16x8*)(Ab + row * 64 + (((kc * 4 + lhalf) ^ (row & 7)) * 8));
      }
#pragma unroll
      for (int j = 0; j < 4; j++) {
        int row = wn + j * 16 + lcol;
        bfr[j] = *(const bf16x8*)(Bb + row * 64 + (((kc * 4 + lhalf) ^ (row & 7)) * 8));
      }
#pragma unroll
      for (int i = 0; i < 4; i++)
#pragma unroll
        for (int j = 0; j < 4; j++)
          acc[i][j] = __builtin_amdgcn_mfma_f32_16x16x32_bf16(af[i], bfr[j], acc[i][j], 0, 0, 0);
    }
    __builtin_amdgcn_s_barrier();
    __builtin_amdgcn_sched_barrier(0);
  }

#pragma unroll
  for (int i = 0; i < 4; i++) {
#pragma unroll
    for (int j = 0; j < 4; j++) {
#pragma unroll
      for (int r = 0; r < 4; r++) {
        int row = m0 + wm + i * 16 + lhalf * 4 + r;
        int col = n0 + wn + j * 16 + lcol;
        float v = acc[i][j][r];
        if (EPI != 5) v += bias[col];
        if (EPI == 2) {
          v = gelu_f(v);
          ((short*)outp)[(size_t)row * N + col] = f2bf(v);
        } else if (EPI == 3) {
          ((short*)outp)[(size_t)row * N + col] = f2bf(v);
        } else {  // EPI 5: bf16 partial
          ((short*)outp)[(size_t)z * M * N + (size_t)row * N + col] = f2bf(v);
        }
      }
    }
  }
}

// ---- Attention (R8-proven body): 64 q/block, 4 waves, z-split 4 ----
// R14: 1D grid of 2048 with XCD-aware decode. Under round-robin dispatch,
// ids = c (mod 8) land on XCD c; we give XCD c only heads {2c, 2c+1}, so
// each XCD's K+V working set is 1.05 MB -> L2-resident, eliminating the
// ~8x cross-XCD K/V re-fetch (32 q-blocks share each (head,z) panel) and
// dropping staging latency from HBM-class to L2-class. Pure permutation.
__global__ __launch_bounds__(256) void attn_kernel(
    const short* __restrict__ Qh, const short* __restrict__ Kh,
    const short* __restrict__ Vt, const int* __restrict__ offs,
    short* __restrict__ Opart, float* __restrict__ Lpart) {
  __shared__ __attribute__((aligned(16))) short Klds[64 * 64];
  __shared__ __attribute__((aligned(16))) short Vlds[64 * 64];
  __shared__ __attribute__((aligned(16))) unsigned int Plds[4][16 * 34];
  int id   = blockIdx.x;
  int head = ((id & 7) << 1) | ((id >> 3) & 1);  // XCD (id&7) -> heads {2c,2c+1}
  int rest = id >> 4;                             // 0..127
  int q0   = (rest & 31) * 64;
  int z    = rest >> 5;                           // 0..3
  int tid  = threadIdx.x;
  int w    = tid >> 6;
  int lane = tid & 63;
  int lcol = lane & 15;
  int h    = lane >> 4;
  int s7   = lcol & 7;
  int o1 = offs[1], o2 = offs[2], o3 = offs[3];

  int qrow = q0 + w * 16 + lcol;
  const short* qb = Qh + ((size_t)head * SEQ + qrow) * HD;
  bf16x8 qf0 = *(const bf16x8*)(qb + h * 8);
  bf16x8 qf1 = *(const bf16x8*)(qb + 32 + h * 8);
  int sq = (qrow >= o1) + (qrow >= o2) + (qrow >= o3);
  U8 qe;
  qe.u[0] = 0; qe.u[1] = 0; qe.u[2] = 0; qe.u[3] = 0;
  if (h == 0) qe.s[sq] = (short)0x3FB9;  // bf16(log2e)

  bf16x8 ones;
#pragma unroll
  for (int i = 0; i < 8; i++) ones[i] = 0x3F80;

  int kb0 = lcol * 64 + ((h ^ s7) * 8);
  int kb1 = lcol * 64 + (((4 + h) ^ s7) * 8);
  int vb0 = kb0, vb1 = kb1;
  int pwb = lcol * 34 + h * 2;
  int prb = lcol * 34 + h * 4;

  int tbeg = z * 512;
  const short* kp0; const short* kp1; const short* vp0; const short* vp1;
  {
    int seg = tid, row = seg >> 3, g = (seg & 7) ^ (row & 7);
    kp0 = Kh + ((size_t)head * SEQ + tbeg + row) * HD + g * 8;
    vp0 = Vt + ((size_t)head * HD + row) * SEQ + tbeg + g * 8;
    seg = 256 + tid; row = seg >> 3; g = (seg & 7) ^ (row & 7);
    kp1 = Kh + ((size_t)head * SEQ + tbeg + row) * HD + g * 8;
    vp1 = Vt + ((size_t)head * HD + row) * SEQ + tbeg + g * 8;
  }

  f32x4 o_acc[4];
#pragma unroll
  for (int nt = 0; nt < 4; nt++) o_acc[nt] = (f32x4){0.f, 0.f, 0.f, 0.f};
  f32x4 acc_l = (f32x4){0.f, 0.f, 0.f, 0.f};

  for (int t0 = 0; t0 < 512; t0 += 64) {
    async_cp16(kp0, Klds + w * 512);          kp0 += 64 * HD;
    async_cp16(kp1, Klds + 2048 + w * 512);   kp1 += 64 * HD;
    async_cp16(vp0, Vlds + w * 512);          vp0 += 64;
    async_cp16(vp1, Vlds + 2048 + w * 512);   vp1 += 64;
    __syncthreads();

#pragma unroll
    for (int n = 0; n < 4; n++) {
      bf16x8 kf0 = *(const bf16x8*)(Klds + n * 1024 + kb0);
      bf16x8 kf1 = *(const bf16x8*)(Klds + n * 1024 + kb1);
      int key = tbeg + t0 + n * 16 + lcol;
      int sk = (key >= o1) + (key >= o2) + (key >= o3);
      U8 ke;
      ke.u[0] = (h == 0) ? ((sk == 0) ? 0x00003F80u : (sk == 1) ? 0x3F800000u : 0u) : 0u;
      ke.u[1] = (h == 0) ? ((sk == 2) ? 0x00003F80u : (sk == 3) ? 0x3F800000u : 0u) : 0u;
      ke.u[2] = 0; ke.u[3] = 0;

      f32x4 sacc = (f32x4){0.f, 0.f, 0.f, 0.f};
      sacc = __builtin_amdgcn_mfma_f32_16x16x32_bf16(kf0, qf0, sacc, 0, 0, 0);
      sacc = __builtin_amdgcn_mfma_f32_16x16x32_bf16(kf1, qf1, sacc, 0, 0, 0);
      sacc = __builtin_amdgcn_mfma_f32_16x16x32_bf16(ke.v, qe.v, sacc, 0, 0, 0);

      float p0 = fast_exp2(sacc[0]);
      float p1 = fast_exp2(sacc[1]);
      float p2 = fast_exp2(sacc[2]);
      float p3 = fast_exp2(sacc[3]);
      uint2 pw;
      pw.x = __builtin_amdgcn_perm(__float_as_uint(p1), __float_as_uint(p0), 0x07060302);
      pw.y = __builtin_amdgcn_perm(__float_as_uint(p3), __float_as_uint(p2), 0x07060302);
      *(uint2*)&Plds[w][pwb + n * 8] = pw;
    }

#pragma unroll
    for (int kc = 0; kc < 2; kc++) {
      uint2 a = *(const uint2*)&Plds[w][prb + kc * 16];
      uint2 b = *(const uint2*)&Plds[w][prb + kc * 16 + 2];
      U8 pu;
      pu.u[0] = a.x; pu.u[1] = a.y; pu.u[2] = b.x; pu.u[3] = b.y;
      int vb = kc ? vb1 : vb0;
#pragma unroll
      for (int nt = 0; nt < 4; nt++) {
        bf16x8 vf = *(const bf16x8*)(Vlds + nt * 1024 + vb);
        o_acc[nt] = __builtin_amdgcn_mfma_f32_16x16x32_bf16(vf, pu.v, o_acc[nt], 0, 0, 0);
      }
      acc_l = __builtin_amdgcn_mfma_f32_16x16x32_bf16(ones, pu.v, acc_l, 0, 0, 0);
    }
    __syncthreads();
  }

  short* op = Opart + ((size_t)z * SEQ + qrow) * HID + head * HD + h * 4;
#pragma unroll
  for (int nt = 0; nt < 4; nt++) {
    uint2 ua;
    ua.x = pkbf(o_acc[nt][0], o_acc[nt][1]);
    ua.y = pkbf(o_acc[nt][2], o_acc[nt][3]);
    *(uint2*)(op + nt * 16) = ua;
  }
  if (lane < 16)
    Lpart[((size_t)z * NH + head) * SEQ + qrow] = acc_l[0];
}

// ---- merge 4 bf16 z-partials, normalize by sum(l), out bf16 ----
__global__ __launch_bounds__(256) void attn_merge_kernel(
    const short* __restrict__ Opart, const float* __restrict__ Lpart,
    short* __restrict__ attn) {
  int i = blockIdx.x * blockDim.x + threadIdx.x;
  int col4 = i & 255;
  int row  = i >> 8;
  int head = col4 >> 4;
  float acc0 = 0.f, acc1 = 0.f, acc2 = 0.f, acc3 = 0.f, l = 0.f;
#pragma unroll
  for (int zz = 0; zz < 4; zz++) {
    uint2 p = ((const uint2*)(Opart + (size_t)zz * SEQ * HID))[i];
    acc0 += bf2f_lo(p.x); acc1 += bf2f_hi(p.x);
    acc2 += bf2f_lo(p.y); acc3 += bf2f_hi(p.y);
    l += Lpart[((size_t)zz * NH + head) * SEQ + row];
  }
  float rl = fast_rcp(l);
  uint2 o;
  o.x = pkbf(acc0 * rl, acc1 * rl);
  o.y = pkbf(acc2 * rl, acc3 * rl);
  ((uint2*)attn)[i] = o;
}

// ------- split-K bf16-partial merge + bias + residual + LayerNorm -------
__global__ __launch_bounds__(256) void merge_ln_kernel(
    const short* __restrict__ part, const float* __restrict__ bias,
    const float* __restrict__ resid, const float* __restrict__ w,
    const float* __restrict__ b, float* __restrict__ x1, short* __restrict__ h1) {
  int row = blockIdx.x;
  int tid = threadIdx.x;
  size_t idx = (size_t)row * HID / 4 + tid;
  float4 v = {0.f, 0.f, 0.f, 0.f};
#pragma unroll
  for (int z = 0; z < 4; z++) {
    uint2 p = ((const uint2*)(part + (size_t)z * SEQ * HID))[idx];
    v.x += bf2f_lo(p.x); v.y += bf2f_hi(p.x);
    v.z += bf2f_lo(p.y); v.w += bf2f_hi(p.y);
  }
  float4 bi = ((const float4*)bias)[tid];
  float4 rs4 = ((const float4*)(resid + (size_t)row * HID))[tid];
  v.x += bi.x + rs4.x; v.y += bi.y + rs4.y; v.z += bi.z + rs4.z; v.w += bi.w + rs4.w;
  ((float4*)(x1 + (size_t)row * HID))[tid] = v;
  float s  = v.x + v.y + v.z + v.w;
  float s2 = v.x*v.x + v.y*v.y + v.z*v.z + v.w*v.w;
#pragma unroll
  for (int o = 32; o >= 1; o >>= 1) {
    s  += __shfl_xor(s,  o);
    s2 += __shfl_xor(s2, o);
  }
  __shared__ float red[8];
  int wv = tid >> 6;
  if ((tid & 63) == 0) { red[wv] = s; red[4 + wv] = s2; }
  __syncthreads();
  float ts  = red[0] + red[1] + red[2] + red[3];
  float ts2 = red[4] + red[5] + red[6] + red[7];
  float mean = ts * (1.0f / HID);
  float var  = ts2 * (1.0f / HID) - mean * mean;
  float rsq = rsqrtf(var + 1e-5f);
  float4 wv4 = ((const float4*)w)[tid];
  float4 bv4 = ((const float4*)b)[tid];
  short4 o;
  o.x = f2bf((v.x - mean) * rsq * wv4.x + bv4.x);
  o.y = f2bf((v.y - mean) * rsq * wv4.y + bv4.y);
  o.z = f2bf((v.z - mean) * rsq * wv4.z + bv4.z);
  o.w = f2bf((v.w - mean) * rsq * wv4.w + bv4.w);
  ((short4*)(h1 + (size_t)row * HID))[tid] = o;
}

// ------- split-K bf16-partial merge + bias + residual -> fp32 out -------
__global__ __launch_bounds__(256) void merge_bias_kernel(
    const short* __restrict__ part, const float* __restrict__ bias,
    const float* __restrict__ resid, float* __restrict__ out) {
  int i = blockIdx.x * blockDim.x + threadIdx.x;
  int col4 = i & 255;
  float4 v = {0.f, 0.f, 0.f, 0.f};
#pragma unroll
  for (int z = 0; z < 4; z++) {
    uint2 p = ((const uint2*)(part + (size_t)z * SEQ * HID))[i];
    v.x += bf2f_lo(p.x); v.y += bf2f_hi(p.x);
    v.z += bf2f_lo(p.y); v.w += bf2f_hi(p.y);
  }
  float4 bi = ((const float4*)bias)[col4];
  float4 rs = ((const float4*)resid)[i];
  float4 o;
  o.x = v.x + bi.x + rs.x;
  o.y = v.y + bi.y + rs.y;
  o.z = v.z + bi.z + rs.z;
  o.w = v.w + bi.w + rs.w;
  ((float4*)out)[i] = o;
}

extern "C" void kernel_launch(void* const* d_in, const int* in_sizes, int n_in,
                              void* d_out, int out_size, void* d_ws, size_t ws_size,
                              hipStream_t stream) {
  const float* x      = (const float*)d_in[0];
  const float* ropec  = (const float*)d_in[1];
  const float* ropes  = (const float*)d_in[2];
  const float* n0w    = (const float*)d_in[3];
  const float* n0b    = (const float*)d_in[4];
  const float* n1w    = (const float*)d_in[5];
  const float* n1b    = (const float*)d_in[6];
  const float* wqkv_w = (const float*)d_in[7];
  const float* wqkv_b = (const float*)d_in[8];
  const float* wo_w   = (const float*)d_in[9];
  const float* wo_b   = (const float*)d_in[10];
  const float* up_w   = (const float*)d_in[11];
  const float* up_b   = (const float*)d_in[12];
  const float* down_w = (const float*)d_in[13];
  const float* down_b = (const float*)d_in[14];
  const int*   offs   = (const int*)d_in[15];
  float* out = (float*)d_out;

  char* base = (char*)d_ws;
  // ---- static layout, lifetime-aliased (peak ~88.6 MB) ----
  short* wqkv_bf = (short*)(base + 0);            //  6.3 MB, whole run
  short* wo_bf   = (short*)(base + 6291456);      //  2.1 MB, whole run
  short* up_bf   = (short*)(base + 8388608);      //  8.4 MB, whole run
  short* down_bf = (short*)(base + 16777216);     //  8.4 MB, whole run
  short* h0      = (short*)(base + 25165824);     //  4.2 MB, dead after qkv gemm
  short* qkv_bf  = (short*)(base + 29360128);     // 12.6 MB, dead after ropev
  short* Qh      = (short*)(base + 41943040);     //  4.2 MB, dead after attn
  short* Kh      = (short*)(base + 46137344);     //  4.2 MB, dead after attn
  short* Vt      = (short*)(base + 50331648);     //  4.2 MB, dead after attn
  short* Opart   = (short*)(base + 54525952);     // 16.8 MB, dead after attn_merge
  float* Lpart   = (float*)(base + 71303168);     //  0.5 MB
  short* attn    = (short*)(base + 71827456);     //  4.2 MB, dead after wo gemm
  float* x1      = (float*)(base + 76021760);     //  8.4 MB, live to end
  short* h1      = (short*)(base + 84410368);     //  4.2 MB, dead after up gemm
  short* wopart  = (short*)(base + 25165824);     // 16.8 MB -> 41.9 MB (h0..Vt dead)
  short* u       = (short*)(base + 25165824);     // 16.8 MB -> 41.9 MB
  short* dnpart  = (short*)(base + 41943040);     // 16.8 MB -> 58.7 MB (Qh..Opart dead)

  cvtln_kernel<<<14336, 256, 0, stream>>>(wqkv_w, wo_w, up_w, down_w,
                                          wqkv_bf, wo_bf, up_bf, down_bf,
                                          x, n0w, n0b, h0);
  gemm_bt_kernel<3><<<dim3(24, 16), 256, 0, stream>>>(h0, wqkv_bf, wqkv_b, nullptr,
                                                      qkv_bf, 2048, 3072, 1024, 1024);
  ropev_kernel<<<dim3(32, 16), 256, 0, stream>>>(qkv_bf, ropec, ropes, Qh, Kh, Vt);
  attn_kernel<<<2048, 256, 0, stream>>>(Qh, Kh, Vt, offs, Opart, Lpart);
  attn_merge_kernel<<<2048, 256, 0, stream>>>(Opart, Lpart, attn);
  gemm_bt_kernel<5><<<dim3(8, 16, 4), 256, 0, stream>>>(attn, wo_bf, nullptr, nullptr,
                                                        wopart, 2048, 1024, 256, 1024);
  merge_ln_kernel<<<2048, 256, 0, stream>>>(wopart, wo_b, x, n1w, n1b, x1, h1);
  gemm_bt_kernel<2><<<dim3(32, 16), 256, 0, stream>>>(h1, up_bf, up_b, nullptr,
                                                      u, 2048, 4096, 1024, 1024);
  gemm_bt_kernel<5><<<dim3(8, 16, 4), 256, 0, stream>>>(u, down_bf, nullptr, nullptr,
                                                        dnpart, 2048, 1024, 1024, 4096);
  merge_bias_kernel<<<2048, 256, 0, stream>>>(dnpart, down_b, x1, out);
}

// Round 7
// 261.867 us; speedup vs baseline: 1.0549x; 1.0094x over previous
//
#include <hip/hip_runtime.h>
#include <hip/hip_bf16.h>
#include <math.h>

#define SEQ 2048
#define HID 1024
#define NH 16
#define HD 64

using f32x4  = __attribute__((ext_vector_type(4))) float;
using bf16x8 = __attribute__((ext_vector_type(8))) short;

union U8 { unsigned int u[4]; bf16x8 v; short s[8]; };

__device__ __forceinline__ short f2bf(float f) {
  unsigned int x = __float_as_uint(f);
  unsigned int r = (x + 0x7fffu + ((x >> 16) & 1u)) >> 16;
  return (short)(r & 0xffffu);
}

__device__ __forceinline__ unsigned int pkbf(float a, float b) {
  return ((unsigned int)(unsigned short)f2bf(a)) |
         (((unsigned int)(unsigned short)f2bf(b)) << 16);
}

__device__ __forceinline__ float bf2f_lo(unsigned int u) {
  return __uint_as_float((u & 0xffffu) << 16);
}
__device__ __forceinline__ float bf2f_hi(unsigned int u) {
  return __uint_as_float(u & 0xffff0000u);
}

__device__ __forceinline__ float fast_exp2(float x) {
#if __has_builtin(__builtin_amdgcn_exp2f)
  return __builtin_amdgcn_exp2f(x);
#else
  return exp2f(x);
#endif
}

__device__ __forceinline__ float fast_rcp(float x) {
#if __has_builtin(__builtin_amdgcn_rcpf)
  return __builtin_amdgcn_rcpf(x);
#else
  return 1.0f / x;
#endif
}

__device__ __forceinline__ float gelu_f(float v) {
  float t = v * (1.5957691216057308f + 0.07135481283942279f * v * v);
  float e = fast_exp2(t * -1.4426950408889634f);
  return v * fast_rcp(1.0f + e);
}

__device__ __forceinline__ void async_cp16(const void* g, void* l) {
  __builtin_amdgcn_global_load_lds(
      (__attribute__((address_space(1))) void*)(g),
      (__attribute__((address_space(3))) void*)(l), 16, 0, 0);
}

// ------- fused: fp32->bf16 weight cvt (blocks 2048..14335) + LayerNorm0
// (blocks 0..2047). Independent work, one launch. -------
__global__ __launch_bounds__(256) void cvtln_kernel(
    const float* __restrict__ a, const float* __restrict__ b,
    const float* __restrict__ c, const float* __restrict__ d,
    short* __restrict__ oa, short* __restrict__ ob,
    short* __restrict__ oc, short* __restrict__ od,
    const float* __restrict__ x, const float* __restrict__ w,
    const float* __restrict__ bb, short* __restrict__ h0) {
  int tid = threadIdx.x;
  if (blockIdx.x < 2048) {
    int row = blockIdx.x;
    float4 v = ((const float4*)(x + (size_t)row * HID))[tid];
    float s  = v.x + v.y + v.z + v.w;
    float s2 = v.x*v.x + v.y*v.y + v.z*v.z + v.w*v.w;
#pragma unroll
    for (int o = 32; o >= 1; o >>= 1) {
      s  += __shfl_xor(s,  o);
      s2 += __shfl_xor(s2, o);
    }
    __shared__ float red[8];
    int wv = tid >> 6;
    if ((tid & 63) == 0) { red[wv] = s; red[4 + wv] = s2; }
    __syncthreads();
    float ts  = red[0] + red[1] + red[2] + red[3];
    float ts2 = red[4] + red[5] + red[6] + red[7];
    float mean = ts * (1.0f / HID);
    float var  = ts2 * (1.0f / HID) - mean * mean;
    float rs = rsqrtf(var + 1e-5f);
    float4 wv4 = ((const float4*)w)[tid];
    float4 bv4 = ((const float4*)bb)[tid];
    short4 o;
    o.x = f2bf((v.x - mean) * rs * wv4.x + bv4.x);
    o.y = f2bf((v.y - mean) * rs * wv4.y + bv4.y);
    o.z = f2bf((v.z - mean) * rs * wv4.z + bv4.z);
    o.w = f2bf((v.w - mean) * rs * wv4.w + bv4.w);
    ((short4*)(h0 + (size_t)row * HID))[tid] = o;
    return;
  }
  int i = (blockIdx.x - 2048) * 256 + tid;  // float4 index, 3145728 total
  const float* src; short* dst; int off;
  if (i < 786432)        { src = a; dst = oa; off = i; }
  else if (i < 1048576)  { src = b; dst = ob; off = i - 786432; }
  else if (i < 2097152)  { src = c; dst = oc; off = i - 1048576; }
  else                   { src = d; dst = od; off = i - 2097152; }
  float4 v = ((const float4*)src)[off];
  short4 o;
  o.x = f2bf(v.x); o.y = f2bf(v.y); o.z = f2bf(v.z); o.w = f2bf(v.w);
  ((short4*)dst)[off] = o;
}

// ---- Fused RoPE(q,k) + V-transpose, per (s0-block of 64, head) ----
__global__ __launch_bounds__(256) void ropev_kernel(const short* __restrict__ qkvb,
    const float* __restrict__ cosb, const float* __restrict__ sinb,
    short* __restrict__ Qh, short* __restrict__ Kh, short* __restrict__ Vt) {
  __shared__ short tile[64 * 72];
  int s0   = blockIdx.x * 64;
  int head = blockIdx.y;
  int tid  = threadIdx.x;
#pragma unroll
  for (int p = 0; p < 2; p++) {
    int seg = p * 256 + tid;
    int row = seg >> 3;
    int c8  = seg & 7;
    bf16x8 v = *(const bf16x8*)(qkvb + (size_t)(s0 + row) * 3072 + 2048 + head * 64 + c8 * 8);
    *(bf16x8*)(tile + row * 72 + c8 * 8) = v;
  }
  int sl = tid >> 3;
  int c  = tid & 7;
#pragma unroll
  for (int j = 0; j < 2; j++) {        // 0 = q, 1 = k
    float scale = (j == 0) ? 0.18033688011112043f : 1.0f;  // 0.125*log2(e)
    short* dstm = (j == 0) ? Qh : Kh;
#pragma unroll
    for (int half = 0; half < 2; half++) {
      int s = s0 + half * 32 + sl;
      uint4 uu = *(const uint4*)(qkvb + (size_t)s * 3072 + j * 1024 + head * 64 + c * 8);
      float4 cs = *(const float4*)(cosb + s * 32 + c * 4);
      float4 sn = *(const float4*)(sinb + s * 32 + c * 4);
      uint4 oo;
      {
        float a = bf2f_lo(uu.x), b = bf2f_hi(uu.x);
        oo.x = pkbf(scale * (a * cs.x - b * sn.x), scale * (a * sn.x + b * cs.x));
        a = bf2f_lo(uu.y); b = bf2f_hi(uu.y);
        oo.y = pkbf(scale * (a * cs.y - b * sn.y), scale * (a * sn.y + b * cs.y));
        a = bf2f_lo(uu.z); b = bf2f_hi(uu.z);
        oo.z = pkbf(scale * (a * cs.z - b * sn.z), scale * (a * sn.z + b * cs.z));
        a = bf2f_lo(uu.w); b = bf2f_hi(uu.w);
        oo.w = pkbf(scale * (a * cs.w - b * sn.w), scale * (a * sn.w + b * cs.w));
      }
      *(uint4*)(dstm + ((size_t)head * SEQ + s) * HD + c * 8) = oo;
    }
  }
  __syncthreads();
#pragma unroll
  for (int p = 0; p < 2; p++) {
    int seg = p * 256 + tid;
    int d   = seg >> 3;
    int sc  = seg & 7;
    U8 o;
#pragma unroll
    for (int jj = 0; jj < 8; jj++) o.s[jj] = tile[(sc * 8 + jj) * 72 + d];
    *(bf16x8*)(Vt + ((size_t)head * HD + d) * SEQ + s0 + sc * 8) = o.v;
  }
}

// ---------------- GEMM: C(MxN) = A(MxK) * B(NxK)^T, bf16 MFMA, BK=64 -------
// LDS pitch 64 shorts, slot = chunk ^ (row&7) (bank-even, verified symbolically).
// R10-proven dbuf: 64 KB ping-pong + counted vmcnt(8) + raw s_barrier.
// R15: 1D grid + bijective per-XCD RECTANGLE decode. R14's attn experiment
// proved id%8 -> XCD round-robin holds on this machine (FETCH 38->8 MB).
// GEMM operand re-fetch (N/BN x A + M/BM x B ~ 870 MB total) currently
// misses per-XCD L2 because consecutive tiles round-robin across XCDs.
// Each XCD now owns a contiguous (x,y,z) rectangle -> 4-6 MB working set,
// L2-resident. Decode: xcd=id&7, lid=id>>3; chunk grid (ncx,ncy) of
// (cx,cy)-tile rectangles; z from remaining bits. Pure permutation.
// EPI 2: gelu bf16, EPI 3: bias bf16, EPI 5: split-K bf16 partial
template <int EPI>
__global__ __launch_bounds__(256) void gemm_bt_kernel(
    const short* __restrict__ A, const short* __restrict__ B,
    const float* __restrict__ bias, const float* __restrict__ resid,
    void* __restrict__ outp, int M, int N, int Klen, int Kstride,
    int cx, int cy, int ncx, int ncy, int cz) {
  __shared__ __attribute__((aligned(16))) short Alds[2 * 128 * 64];
  __shared__ __attribute__((aligned(16))) short Blds[2 * 128 * 64];
  int tid = threadIdx.x;
  int w    = tid >> 6;
  int lane = tid & 63;
  int lcol  = lane & 15;
  int lhalf = lane >> 4;

  // XCD-rectangle decode (bijective for all launch configs below)
  int xcd = blockIdx.x & 7;
  int lid = blockIdx.x >> 3;
  int cix = xcd % ncx;
  int tt  = xcd / ncx;
  int ciy = tt % ncy;
  int ciz = tt / ncy;
  int xx  = cix * cx + lid % cx;
  int rr  = lid / cx;
  int yy  = ciy * cy + rr % cy;
  int z   = ciz * cz + rr / cy;

  int m0 = yy * 128;
  int n0 = xx * 128;
  int wm = (w & 1) * 64;
  int wn = (w >> 1) * 64;

  // staging: 4 cp16 rounds per buffer; global chunk swizzled by row&7
  const short* apt[4];
  const short* bpt[4];
#pragma unroll
  for (int p = 0; p < 4; p++) {
    int seg = p * 256 + tid;
    int row = seg >> 3;
    int c   = (seg & 7) ^ (row & 7);
    apt[p] = A + (size_t)z * Klen + (size_t)(m0 + row) * Kstride + c * 8;
    bpt[p] = B + (size_t)z * Klen + (size_t)(n0 + row) * Kstride + c * 8;
  }

  f32x4 acc[4][4];
#pragma unroll
  for (int i = 0; i < 4; i++)
#pragma unroll
    for (int j = 0; j < 4; j++) acc[i][j] = (f32x4){0.f, 0.f, 0.f, 0.f};

  int nk = Klen >> 6;
  // prologue: stage K-tile 0 into buffer 0
#pragma unroll
  for (int p = 0; p < 4; p++) {
    async_cp16(apt[p], Alds + p * 2048 + w * 512);  apt[p] += 64;
    async_cp16(bpt[p], Blds + p * 2048 + w * 512);  bpt[p] += 64;
  }
  for (int kt = 0; kt < nk; ++kt) {
    int cur = kt & 1;
    const short* Ab = Alds + cur * 8192;
    const short* Bb = Blds + cur * 8192;
    if (kt + 1 < nk) {
      int nb = (cur ^ 1) * 8192;
#pragma unroll
      for (int p = 0; p < 4; p++) {
        async_cp16(apt[p], Alds + nb + p * 2048 + w * 512);  apt[p] += 64;
        async_cp16(bpt[p], Blds + nb + p * 2048 + w * 512);  bpt[p] += 64;
      }
      asm volatile("s_waitcnt vmcnt(8)" ::: "memory");  // tile kt landed
    } else {
      asm volatile("s_waitcnt vmcnt(0)" ::: "memory");
    }
    __builtin_amdgcn_s_barrier();
    __builtin_amdgcn_sched_barrier(0);
#pragma unroll
    for (int kc = 0; kc < 2; kc++) {
      bf16x8 af[4], bfr[4];
#pragma unroll
      for (int i = 0; i < 4; i++) {
        int row = wm + i * 16 + lcol;
        af[i] = *(const bf16x8*)(Ab + row * 64 + (((kc * 4 + lhalf) ^ (row & 7)) * 8));
      }
#pragma unroll
      for (int j = 0; j < 4; j++) {
        int row = wn + j * 16 + lcol;
        bfr[j] = *(const bf16x8*)(Bb + row * 64 + (((kc * 4 + lhalf) ^ (row & 7)) * 8));
      }
#pragma unroll
      for (int i = 0; i < 4; i++)
#pragma unroll
        for (int j = 0; j < 4; j++)
          acc[i][j] = __builtin_amdgcn_mfma_f32_16x16x32_bf16(af[i], bfr[j], acc[i][j], 0, 0, 0);
    }
    __builtin_amdgcn_s_barrier();
    __builtin_amdgcn_sched_barrier(0);
  }

#pragma unroll
  for (int i = 0; i < 4; i++) {
#pragma unroll
    for (int j = 0; j < 4; j++) {
#pragma unroll
      for (int r = 0; r < 4; r++) {
        int row = m0 + wm + i * 16 + lhalf * 4 + r;
        int col = n0 + wn + j * 16 + lcol;
        float v = acc[i][j][r];
        if (EPI != 5) v += bias[col];
        if (EPI == 2) {
          v = gelu_f(v);
          ((short*)outp)[(size_t)row * N + col] = f2bf(v);
        } else if (EPI == 3) {
          ((short*)outp)[(size_t)row * N + col] = f2bf(v);
        } else {  // EPI 5: bf16 partial
          ((short*)outp)[(size_t)z * M * N + (size_t)row * N + col] = f2bf(v);
        }
      }
    }
  }
}

// ---- Attention (R8-proven, reverted exactly): 64 q/block, 4 waves, z=4 ----
// Six rounds of evidence: time ~42 us invariant to TLP (R12), LDS traffic
// (R13, worse), HBM fetch (R14, worse). Structural floor for this per-wave
// algorithm; leave untouched.
__global__ __launch_bounds__(256) void attn_kernel(
    const short* __restrict__ Qh, const short* __restrict__ Kh,
    const short* __restrict__ Vt, const int* __restrict__ offs,
    short* __restrict__ Opart, float* __restrict__ Lpart) {
  __shared__ __attribute__((aligned(16))) short Klds[64 * 64];
  __shared__ __attribute__((aligned(16))) short Vlds[64 * 64];
  __shared__ __attribute__((aligned(16))) unsigned int Plds[4][16 * 34];
  int head = blockIdx.y;
  int q0   = blockIdx.x * 64;
  int z    = blockIdx.z;
  int tid  = threadIdx.x;
  int w    = tid >> 6;
  int lane = tid & 63;
  int lcol = lane & 15;
  int h    = lane >> 4;
  int s7   = lcol & 7;
  int o1 = offs[1], o2 = offs[2], o3 = offs[3];

  int qrow = q0 + w * 16 + lcol;
  const short* qb = Qh + ((size_t)head * SEQ + qrow) * HD;
  bf16x8 qf0 = *(const bf16x8*)(qb + h * 8);
  bf16x8 qf1 = *(const bf16x8*)(qb + 32 + h * 8);
  int sq = (qrow >= o1) + (qrow >= o2) + (qrow >= o3);
  U8 qe;
  qe.u[0] = 0; qe.u[1] = 0; qe.u[2] = 0; qe.u[3] = 0;
  if (h == 0) qe.s[sq] = (short)0x3FB9;  // bf16(log2e)

  bf16x8 ones;
#pragma unroll
  for (int i = 0; i < 8; i++) ones[i] = 0x3F80;

  int kb0 = lcol * 64 + ((h ^ s7) * 8);
  int kb1 = lcol * 64 + (((4 + h) ^ s7) * 8);
  int vb0 = kb0, vb1 = kb1;
  int pwb = lcol * 34 + h * 2;
  int prb = lcol * 34 + h * 4;

  int tbeg = z * 512;
  const short* kp0; const short* kp1; const short* vp0; const short* vp1;
  {
    int seg = tid, row = seg >> 3, g = (seg & 7) ^ (row & 7);
    kp0 = Kh + ((size_t)head * SEQ + tbeg + row) * HD + g * 8;
    vp0 = Vt + ((size_t)head * HD + row) * SEQ + tbeg + g * 8;
    seg = 256 + tid; row = seg >> 3; g = (seg & 7) ^ (row & 7);
    kp1 = Kh + ((size_t)head * SEQ + tbeg + row) * HD + g * 8;
    vp1 = Vt + ((size_t)head * HD + row) * SEQ + tbeg + g * 8;
  }

  f32x4 o_acc[4];
#pragma unroll
  for (int nt = 0; nt < 4; nt++) o_acc[nt] = (f32x4){0.f, 0.f, 0.f, 0.f};
  f32x4 acc_l = (f32x4){0.f, 0.f, 0.f, 0.f};

  for (int t0 = 0; t0 < 512; t0 += 64) {
    async_cp16(kp0, Klds + w * 512);          kp0 += 64 * HD;
    async_cp16(kp1, Klds + 2048 + w * 512);   kp1 += 64 * HD;
    async_cp16(vp0, Vlds + w * 512);          vp0 += 64;
    async_cp16(vp1, Vlds + 2048 + w * 512);   vp1 += 64;
    __syncthreads();

#pragma unroll
    for (int n = 0; n < 4; n++) {
      bf16x8 kf0 = *(const bf16x8*)(Klds + n * 1024 + kb0);
      bf16x8 kf1 = *(const bf16x8*)(Klds + n * 1024 + kb1);
      int key = tbeg + t0 + n * 16 + lcol;
      int sk = (key >= o1) + (key >= o2) + (key >= o3);
      U8 ke;
      ke.u[0] = (h == 0) ? ((sk == 0) ? 0x00003F80u : (sk == 1) ? 0x3F800000u : 0u) : 0u;
      ke.u[1] = (h == 0) ? ((sk == 2) ? 0x00003F80u : (sk == 3) ? 0x3F800000u : 0u) : 0u;
      ke.u[2] = 0; ke.u[3] = 0;

      f32x4 sacc = (f32x4){0.f, 0.f, 0.f, 0.f};
      sacc = __builtin_amdgcn_mfma_f32_16x16x32_bf16(kf0, qf0, sacc, 0, 0, 0);
      sacc = __builtin_amdgcn_mfma_f32_16x16x32_bf16(kf1, qf1, sacc, 0, 0, 0);
      sacc = __builtin_amdgcn_mfma_f32_16x16x32_bf16(ke.v, qe.v, sacc, 0, 0, 0);

      float p0 = fast_exp2(sacc[0]);
      float p1 = fast_exp2(sacc[1]);
      float p2 = fast_exp2(sacc[2]);
      float p3 = fast_exp2(sacc[3]);
      uint2 pw;
      pw.x = __builtin_amdgcn_perm(__float_as_uint(p1), __float_as_uint(p0), 0x07060302);
      pw.y = __builtin_amdgcn_perm(__float_as_uint(p3), __float_as_uint(p2), 0x07060302);
      *(uint2*)&Plds[w][pwb + n * 8] = pw;
    }

#pragma unroll
    for (int kc = 0; kc < 2; kc++) {
      uint2 a = *(const uint2*)&Plds[w][prb + kc * 16];
      uint2 b = *(const uint2*)&Plds[w][prb + kc * 16 + 2];
      U8 pu;
      pu.u[0] = a.x; pu.u[1] = a.y; pu.u[2] = b.x; pu.u[3] = b.y;
      int vb = kc ? vb1 : vb0;
#pragma unroll
      for (int nt = 0; nt < 4; nt++) {
        bf16x8 vf = *(const bf16x8*)(Vlds + nt * 1024 + vb);
        o_acc[nt] = __builtin_amdgcn_mfma_f32_16x16x32_bf16(vf, pu.v, o_acc[nt], 0, 0, 0);
      }
      acc_l = __builtin_amdgcn_mfma_f32_16x16x32_bf16(ones, pu.v, acc_l, 0, 0, 0);
    }
    __syncthreads();
  }

  short* op = Opart + ((size_t)z * SEQ + qrow) * HID + head * HD + h * 4;
#pragma unroll
  for (int nt = 0; nt < 4; nt++) {
    uint2 ua;
    ua.x = pkbf(o_acc[nt][0], o_acc[nt][1]);
    ua.y = pkbf(o_acc[nt][2], o_acc[nt][3]);
    *(uint2*)(op + nt * 16) = ua;
  }
  if (lane < 16)
    Lpart[((size_t)z * NH + head) * SEQ + qrow] = acc_l[0];
}

// ---- merge 4 bf16 z-partials, normalize by sum(l), out bf16 ----
__global__ __launch_bounds__(256) void attn_merge_kernel(
    const short* __restrict__ Opart, const float* __restrict__ Lpart,
    short* __restrict__ attn) {
  int i = blockIdx.x * blockDim.x + threadIdx.x;
  int col4 = i & 255;
  int row  = i >> 8;
  int head = col4 >> 4;
  float acc0 = 0.f, acc1 = 0.f, acc2 = 0.f, acc3 = 0.f, l = 0.f;
#pragma unroll
  for (int zz = 0; zz < 4; zz++) {
    uint2 p = ((const uint2*)(Opart + (size_t)zz * SEQ * HID))[i];
    acc0 += bf2f_lo(p.x); acc1 += bf2f_hi(p.x);
    acc2 += bf2f_lo(p.y); acc3 += bf2f_hi(p.y);
    l += Lpart[((size_t)zz * NH + head) * SEQ + row];
  }
  float rl = fast_rcp(l);
  uint2 o;
  o.x = pkbf(acc0 * rl, acc1 * rl);
  o.y = pkbf(acc2 * rl, acc3 * rl);
  ((uint2*)attn)[i] = o;
}

// ------- split-K bf16-partial merge + bias + residual + LayerNorm -------
__global__ __launch_bounds__(256) void merge_ln_kernel(
    const short* __restrict__ part, const float* __restrict__ bias,
    const float* __restrict__ resid, const float* __restrict__ w,
    const float* __restrict__ b, float* __restrict__ x1, short* __restrict__ h1) {
  int row = blockIdx.x;
  int tid = threadIdx.x;
  size_t idx = (size_t)row * HID / 4 + tid;
  float4 v = {0.f, 0.f, 0.f, 0.f};
#pragma unroll
  for (int z = 0; z < 4; z++) {
    uint2 p = ((const uint2*)(part + (size_t)z * SEQ * HID))[idx];
    v.x += bf2f_lo(p.x); v.y += bf2f_hi(p.x);
    v.z += bf2f_lo(p.y); v.w += bf2f_hi(p.y);
  }
  float4 bi = ((const float4*)bias)[tid];
  float4 rs4 = ((const float4*)(resid + (size_t)row * HID))[tid];
  v.x += bi.x + rs4.x; v.y += bi.y + rs4.y; v.z += bi.z + rs4.z; v.w += bi.w + rs4.w;
  ((float4*)(x1 + (size_t)row * HID))[tid] = v;
  float s  = v.x + v.y + v.z + v.w;
  float s2 = v.x*v.x + v.y*v.y + v.z*v.z + v.w*v.w;
#pragma unroll
  for (int o = 32; o >= 1; o >>= 1) {
    s  += __shfl_xor(s,  o);
    s2 += __shfl_xor(s2, o);
  }
  __shared__ float red[8];
  int wv = tid >> 6;
  if ((tid & 63) == 0) { red[wv] = s; red[4 + wv] = s2; }
  __syncthreads();
  float ts  = red[0] + red[1] + red[2] + red[3];
  float ts2 = red[4] + red[5] + red[6] + red[7];
  float mean = ts * (1.0f / HID);
  float var  = ts2 * (1.0f / HID) - mean * mean;
  float rsq = rsqrtf(var + 1e-5f);
  float4 wv4 = ((const float4*)w)[tid];
  float4 bv4 = ((const float4*)b)[tid];
  short4 o;
  o.x = f2bf((v.x - mean) * rsq * wv4.x + bv4.x);
  o.y = f2bf((v.y - mean) * rsq * wv4.y + bv4.y);
  o.z = f2bf((v.z - mean) * rsq * wv4.z + bv4.z);
  o.w = f2bf((v.w - mean) * rsq * wv4.w + bv4.w);
  ((short4*)(h1 + (size_t)row * HID))[tid] = o;
}

// ------- split-K bf16-partial merge + bias + residual -> fp32 out -------
__global__ __launch_bounds__(256) void merge_bias_kernel(
    const short* __restrict__ part, const float* __restrict__ bias,
    const float* __restrict__ resid, float* __restrict__ out) {
  int i = blockIdx.x * blockDim.x + threadIdx.x;
  int col4 = i & 255;
  float4 v = {0.f, 0.f, 0.f, 0.f};
#pragma unroll
  for (int z = 0; z < 4; z++) {
    uint2 p = ((const uint2*)(part + (size_t)z * SEQ * HID))[i];
    v.x += bf2f_lo(p.x); v.y += bf2f_hi(p.x);
    v.z += bf2f_lo(p.y); v.w += bf2f_hi(p.y);
  }
  float4 bi = ((const float4*)bias)[col4];
  float4 rs = ((const float4*)resid)[i];
  float4 o;
  o.x = v.x + bi.x + rs.x;
  o.y = v.y + bi.y + rs.y;
  o.z = v.z + bi.z + rs.z;
  o.w = v.w + bi.w + rs.w;
  ((float4*)out)[i] = o;
}

extern "C" void kernel_launch(void* const* d_in, const int* in_sizes, int n_in,
                              void* d_out, int out_size, void* d_ws, size_t ws_size,
                              hipStream_t stream) {
  const float* x      = (const float*)d_in[0];
  const float* ropec  = (const float*)d_in[1];
  const float* ropes  = (const float*)d_in[2];
  const float* n0w    = (const float*)d_in[3];
  const float* n0b    = (const float*)d_in[4];
  const float* n1w    = (const float*)d_in[5];
  const float* n1b    = (const float*)d_in[6];
  const float* wqkv_w = (const float*)d_in[7];
  const float* wqkv_b = (const float*)d_in[8];
  const float* wo_w   = (const float*)d_in[9];
  const float* wo_b   = (const float*)d_in[10];
  const float* up_w   = (const float*)d_in[11];
  const float* up_b   = (const float*)d_in[12];
  const float* down_w = (const float*)d_in[13];
  const float* down_b = (const float*)d_in[14];
  const int*   offs   = (const int*)d_in[15];
  float* out = (float*)d_out;

  char* base = (char*)d_ws;
  // ---- static layout, lifetime-aliased (peak ~88.6 MB) ----
  short* wqkv_bf = (short*)(base + 0);            //  6.3 MB, whole run
  short* wo_bf   = (short*)(base + 6291456);      //  2.1 MB, whole run
  short* up_bf   = (short*)(base + 8388608);      //  8.4 MB, whole run
  short* down_bf = (short*)(base + 16777216);     //  8.4 MB, whole run
  short* h0      = (short*)(base + 25165824);     //  4.2 MB, dead after qkv gemm
  short* qkv_bf  = (short*)(base + 29360128);     // 12.6 MB, dead after ropev
  short* Qh      = (short*)(base + 41943040);     //  4.2 MB, dead after attn
  short* Kh      = (short*)(base + 46137344);     //  4.2 MB, dead after attn
  short* Vt      = (short*)(base + 50331648);     //  4.2 MB, dead after attn
  short* Opart   = (short*)(base + 54525952);     // 16.8 MB, dead after attn_merge
  float* Lpart   = (float*)(base + 71303168);     //  0.5 MB
  short* attn    = (short*)(base + 71827456);     //  4.2 MB, dead after wo gemm
  float* x1      = (float*)(base + 76021760);     //  8.4 MB, live to end
  short* h1      = (short*)(base + 84410368);     //  4.2 MB, dead after up gemm
  short* wopart  = (short*)(base + 25165824);     // 16.8 MB -> 41.9 MB (h0..Vt dead)
  short* u       = (short*)(base + 25165824);     // 16.8 MB -> 41.9 MB
  short* dnpart  = (short*)(base + 41943040);     // 16.8 MB -> 58.7 MB (Qh..Opart dead)

  cvtln_kernel<<<14336, 256, 0, stream>>>(wqkv_w, wo_w, up_w, down_w,
                                          wqkv_bf, wo_bf, up_bf, down_bf,
                                          x, n0w, n0b, h0);
  // qkv: 24x x 16y = 384 blocks; XCD rects 6x x 8y (ncx=4, ncy=2)
  gemm_bt_kernel<3><<<384, 256, 0, stream>>>(h0, wqkv_bf, wqkv_b, nullptr,
                                             qkv_bf, 2048, 3072, 1024, 1024,
                                             6, 8, 4, 2, 1);
  ropev_kernel<<<dim3(32, 16), 256, 0, stream>>>(qkv_bf, ropec, ropes, Qh, Kh, Vt);
  attn_kernel<<<dim3(32, 16, 4), 256, 0, stream>>>(Qh, Kh, Vt, offs, Opart, Lpart);
  attn_merge_kernel<<<2048, 256, 0, stream>>>(Opart, Lpart, attn);
  // wo: 8x x 16y x 4z = 512 blocks; XCD rects 8x x 8y x 1z (ncx=1, ncy=2)
  gemm_bt_kernel<5><<<512, 256, 0, stream>>>(attn, wo_bf, nullptr, nullptr,
                                             wopart, 2048, 1024, 256, 1024,
                                             8, 8, 1, 2, 1);
  merge_ln_kernel<<<2048, 256, 0, stream>>>(wopart, wo_b, x, n1w, n1b, x1, h1);
  // up: 32x x 16y = 512 blocks; XCD rects 8x x 8y (ncx=4, ncy=2)
  gemm_bt_kernel<2><<<512, 256, 0, stream>>>(h1, up_bf, up_b, nullptr,
                                             u, 2048, 4096, 1024, 1024,
                                             8, 8, 4, 2, 1);
  // down: 8x x 16y x 4z = 512 blocks; XCD rects 8x x 8y x 1z
  gemm_bt_kernel<5><<<512, 256, 0, stream>>>(u, down_bf, nullptr, nullptr,
                                             dnpart, 2048, 1024, 1024, 4096,
                                             8, 8, 1, 2, 1);
  merge_bias_kernel<<<2048, 256, 0, stream>>>(dnpart, down_b, x1, out);
}

// Round 8
// 255.558 us; speedup vs baseline: 1.0810x; 1.0247x over previous
//
#include <hip/hip_runtime.h>
#include <hip/hip_bf16.h>
#include <math.h>

#define SEQ 2048
#define HID 1024
#define NH 16
#define HD 64

using f32x4  = __attribute__((ext_vector_type(4))) float;
using bf16x8 = __attribute__((ext_vector_type(8))) short;

union U8 { unsigned int u[4]; bf16x8 v; short s[8]; };

__device__ __forceinline__ short f2bf(float f) {
  unsigned int x = __float_as_uint(f);
  unsigned int r = (x + 0x7fffu + ((x >> 16) & 1u)) >> 16;
  return (short)(r & 0xffffu);
}

__device__ __forceinline__ unsigned int pkbf(float a, float b) {
  return ((unsigned int)(unsigned short)f2bf(a)) |
         (((unsigned int)(unsigned short)f2bf(b)) << 16);
}

__device__ __forceinline__ float bf2f_lo(unsigned int u) {
  return __uint_as_float((u & 0xffffu) << 16);
}
__device__ __forceinline__ float bf2f_hi(unsigned int u) {
  return __uint_as_float(u & 0xffff0000u);
}

__device__ __forceinline__ float fast_exp2(float x) {
#if __has_builtin(__builtin_amdgcn_exp2f)
  return __builtin_amdgcn_exp2f(x);
#else
  return exp2f(x);
#endif
}

__device__ __forceinline__ float fast_rcp(float x) {
#if __has_builtin(__builtin_amdgcn_rcpf)
  return __builtin_amdgcn_rcpf(x);
#else
  return 1.0f / x;
#endif
}

__device__ __forceinline__ float gelu_f(float v) {
  float t = v * (1.5957691216057308f + 0.07135481283942279f * v * v);
  float e = fast_exp2(t * -1.4426950408889634f);
  return v * fast_rcp(1.0f + e);
}

__device__ __forceinline__ void async_cp16(const void* g, void* l) {
  __builtin_amdgcn_global_load_lds(
      (__attribute__((address_space(1))) void*)(g),
      (__attribute__((address_space(3))) void*)(l), 16, 0, 0);
}

// ------- fused: fp32->bf16 weight cvt (blocks 2048..14335) + LayerNorm0
// (blocks 0..2047). Independent work, one launch. -------
__global__ __launch_bounds__(256) void cvtln_kernel(
    const float* __restrict__ a, const float* __restrict__ b,
    const float* __restrict__ c, const float* __restrict__ d,
    short* __restrict__ oa, short* __restrict__ ob,
    short* __restrict__ oc, short* __restrict__ od,
    const float* __restrict__ x, const float* __restrict__ w,
    const float* __restrict__ bb, short* __restrict__ h0) {
  int tid = threadIdx.x;
  if (blockIdx.x < 2048) {
    int row = blockIdx.x;
    float4 v = ((const float4*)(x + (size_t)row * HID))[tid];
    float s  = v.x + v.y + v.z + v.w;
    float s2 = v.x*v.x + v.y*v.y + v.z*v.z + v.w*v.w;
#pragma unroll
    for (int o = 32; o >= 1; o >>= 1) {
      s  += __shfl_xor(s,  o);
      s2 += __shfl_xor(s2, o);
    }
    __shared__ float red[8];
    int wv = tid >> 6;
    if ((tid & 63) == 0) { red[wv] = s; red[4 + wv] = s2; }
    __syncthreads();
    float ts  = red[0] + red[1] + red[2] + red[3];
    float ts2 = red[4] + red[5] + red[6] + red[7];
    float mean = ts * (1.0f / HID);
    float var  = ts2 * (1.0f / HID) - mean * mean;
    float rs = rsqrtf(var + 1e-5f);
    float4 wv4 = ((const float4*)w)[tid];
    float4 bv4 = ((const float4*)bb)[tid];
    short4 o;
    o.x = f2bf((v.x - mean) * rs * wv4.x + bv4.x);
    o.y = f2bf((v.y - mean) * rs * wv4.y + bv4.y);
    o.z = f2bf((v.z - mean) * rs * wv4.z + bv4.z);
    o.w = f2bf((v.w - mean) * rs * wv4.w + bv4.w);
    ((short4*)(h0 + (size_t)row * HID))[tid] = o;
    return;
  }
  int i = (blockIdx.x - 2048) * 256 + tid;  // float4 index, 3145728 total
  const float* src; short* dst; int off;
  if (i < 786432)        { src = a; dst = oa; off = i; }
  else if (i < 1048576)  { src = b; dst = ob; off = i - 786432; }
  else if (i < 2097152)  { src = c; dst = oc; off = i - 1048576; }
  else                   { src = d; dst = od; off = i - 2097152; }
  float4 v = ((const float4*)src)[off];
  short4 o;
  o.x = f2bf(v.x); o.y = f2bf(v.y); o.z = f2bf(v.z); o.w = f2bf(v.w);
  ((short4*)dst)[off] = o;
}

// ---- Fused RoPE(q,k) + V-transpose, per (s0-block of 64, head) ----
__global__ __launch_bounds__(256) void ropev_kernel(const short* __restrict__ qkvb,
    const float* __restrict__ cosb, const float* __restrict__ sinb,
    short* __restrict__ Qh, short* __restrict__ Kh, short* __restrict__ Vt) {
  __shared__ short tile[64 * 72];
  int s0   = blockIdx.x * 64;
  int head = blockIdx.y;
  int tid  = threadIdx.x;
#pragma unroll
  for (int p = 0; p < 2; p++) {
    int seg = p * 256 + tid;
    int row = seg >> 3;
    int c8  = seg & 7;
    bf16x8 v = *(const bf16x8*)(qkvb + (size_t)(s0 + row) * 3072 + 2048 + head * 64 + c8 * 8);
    *(bf16x8*)(tile + row * 72 + c8 * 8) = v;
  }
  int sl = tid >> 3;
  int c  = tid & 7;
#pragma unroll
  for (int j = 0; j < 2; j++) {        // 0 = q, 1 = k
    float scale = (j == 0) ? 0.18033688011112043f : 1.0f;  // 0.125*log2(e)
    short* dstm = (j == 0) ? Qh : Kh;
#pragma unroll
    for (int half = 0; half < 2; half++) {
      int s = s0 + half * 32 + sl;
      uint4 uu = *(const uint4*)(qkvb + (size_t)s * 3072 + j * 1024 + head * 64 + c * 8);
      float4 cs = *(const float4*)(cosb + s * 32 + c * 4);
      float4 sn = *(const float4*)(sinb + s * 32 + c * 4);
      uint4 oo;
      {
        float a = bf2f_lo(uu.x), b = bf2f_hi(uu.x);
        oo.x = pkbf(scale * (a * cs.x - b * sn.x), scale * (a * sn.x + b * cs.x));
        a = bf2f_lo(uu.y); b = bf2f_hi(uu.y);
        oo.y = pkbf(scale * (a * cs.y - b * sn.y), scale * (a * sn.y + b * cs.y));
        a = bf2f_lo(uu.z); b = bf2f_hi(uu.z);
        oo.z = pkbf(scale * (a * cs.z - b * sn.z), scale * (a * sn.z + b * cs.z));
        a = bf2f_lo(uu.w); b = bf2f_hi(uu.w);
        oo.w = pkbf(scale * (a * cs.w - b * sn.w), scale * (a * sn.w + b * cs.w));
      }
      *(uint4*)(dstm + ((size_t)head * SEQ + s) * HD + c * 8) = oo;
    }
  }
  __syncthreads();
#pragma unroll
  for (int p = 0; p < 2; p++) {
    int seg = p * 256 + tid;
    int d   = seg >> 3;
    int sc  = seg & 7;
    U8 o;
#pragma unroll
    for (int jj = 0; jj < 8; jj++) o.s[jj] = tile[(sc * 8 + jj) * 72 + d];
    *(bf16x8*)(Vt + ((size_t)head * HD + d) * SEQ + s0 + sc * 8) = o.v;
  }
}

// ---------------- GEMM: C(MxN) = A(MxK) * B(NxK)^T, bf16 MFMA, BK=64 -------
// LDS pitch 64 shorts, slot = chunk ^ (row&7) (bank-even, verified symbolically).
// R16: 8 waves x 512 threads per 128^2 tile (was 4 waves). Per-wave output
// 64x32 (acc 4x2). LDS unchanged (64 KB dbuf) -> still 2 blocks/CU, so
// waves/CU doubles 8 -> 16: the SIMD scheduler gets 2x material to hide
// the per-K-step vmcnt+barrier drain (m114 mechanism; m97 ran ~12 w/CU).
// Same accumulation order per output element -> bit-identical results.
// Counted vmcnt(4) (4 cp16/wave/tile), raw s_barrier, R15 XCD-rect decode.
// EPI 2: gelu bf16, EPI 3: bias bf16, EPI 5: split-K bf16 partial
template <int EPI>
__global__ __launch_bounds__(512) void gemm_bt_kernel(
    const short* __restrict__ A, const short* __restrict__ B,
    const float* __restrict__ bias, const float* __restrict__ resid,
    void* __restrict__ outp, int M, int N, int Klen, int Kstride,
    int cx, int cy, int ncx, int ncy, int cz) {
  __shared__ __attribute__((aligned(16))) short Alds[2 * 128 * 64];
  __shared__ __attribute__((aligned(16))) short Blds[2 * 128 * 64];
  int tid = threadIdx.x;
  int w    = tid >> 6;      // 0..7
  int lane = tid & 63;
  int lcol  = lane & 15;
  int lhalf = lane >> 4;

  // XCD-rectangle decode (bijective for all launch configs below)
  int xcd = blockIdx.x & 7;
  int lid = blockIdx.x >> 3;
  int cix = xcd % ncx;
  int tt  = xcd / ncx;
  int ciy = tt % ncy;
  int ciz = tt / ncy;
  int xx  = cix * cx + lid % cx;
  int rr  = lid / cx;
  int yy  = ciy * cy + rr % cy;
  int z   = ciz * cz + rr / cy;

  int m0 = yy * 128;
  int n0 = xx * 128;
  int wm = (w & 1) * 64;     // 2 wave-rows of 64
  int wn = (w >> 1) * 32;    // 4 wave-cols of 32

  // staging: 2 cp16 rounds per matrix per buffer (512 threads cover
  // 128 rows x 8 chunks in 2 rounds); global chunk swizzled by row&7
  const short* apt[2];
  const short* bpt[2];
#pragma unroll
  for (int p = 0; p < 2; p++) {
    int seg = p * 512 + tid;
    int row = seg >> 3;
    int c   = (seg & 7) ^ (row & 7);
    apt[p] = A + (size_t)z * Klen + (size_t)(m0 + row) * Kstride + c * 8;
    bpt[p] = B + (size_t)z * Klen + (size_t)(n0 + row) * Kstride + c * 8;
  }

  f32x4 acc[4][2];
#pragma unroll
  for (int i = 0; i < 4; i++)
#pragma unroll
    for (int j = 0; j < 2; j++) acc[i][j] = (f32x4){0.f, 0.f, 0.f, 0.f};

  int nk = Klen >> 6;
  // prologue: stage K-tile 0 into buffer 0 (dest = seg*8 shorts)
#pragma unroll
  for (int p = 0; p < 2; p++) {
    async_cp16(apt[p], Alds + p * 4096 + w * 512);  apt[p] += 64;
    async_cp16(bpt[p], Blds + p * 4096 + w * 512);  bpt[p] += 64;
  }
  for (int kt = 0; kt < nk; ++kt) {
    int cur = kt & 1;
    const short* Ab = Alds + cur * 8192;
    const short* Bb = Blds + cur * 8192;
    if (kt + 1 < nk) {
      int nb = (cur ^ 1) * 8192;
#pragma unroll
      for (int p = 0; p < 2; p++) {
        async_cp16(apt[p], Alds + nb + p * 4096 + w * 512);  apt[p] += 64;
        async_cp16(bpt[p], Blds + nb + p * 4096 + w * 512);  bpt[p] += 64;
      }
      asm volatile("s_waitcnt vmcnt(4)" ::: "memory");  // tile kt landed
    } else {
      asm volatile("s_waitcnt vmcnt(0)" ::: "memory");
    }
    __builtin_amdgcn_s_barrier();
    __builtin_amdgcn_sched_barrier(0);
#pragma unroll
    for (int kc = 0; kc < 2; kc++) {
      bf16x8 af[4], bfr[2];
#pragma unroll
      for (int i = 0; i < 4; i++) {
        int row = wm + i * 16 + lcol;
        af[i] = *(const bf16x8*)(Ab + row * 64 + (((kc * 4 + lhalf) ^ (row & 7)) * 8));
      }
#pragma unroll
      for (int j = 0; j < 2; j++) {
        int row = wn + j * 16 + lcol;
        bfr[j] = *(const bf16x8*)(Bb + row * 64 + (((kc * 4 + lhalf) ^ (row & 7)) * 8));
      }
#pragma unroll
      for (int i = 0; i < 4; i++)
#pragma unroll
        for (int j = 0; j < 2; j++)
          acc[i][j] = __builtin_amdgcn_mfma_f32_16x16x32_bf16(af[i], bfr[j], acc[i][j], 0, 0, 0);
    }
    __builtin_amdgcn_s_barrier();
    __builtin_amdgcn_sched_barrier(0);
  }

#pragma unroll
  for (int i = 0; i < 4; i++) {
#pragma unroll
    for (int j = 0; j < 2; j++) {
#pragma unroll
      for (int r = 0; r < 4; r++) {
        int row = m0 + wm + i * 16 + lhalf * 4 + r;
        int col = n0 + wn + j * 16 + lcol;
        float v = acc[i][j][r];
        if (EPI != 5) v += bias[col];
        if (EPI == 2) {
          v = gelu_f(v);
          ((short*)outp)[(size_t)row * N + col] = f2bf(v);
        } else if (EPI == 3) {
          ((short*)outp)[(size_t)row * N + col] = f2bf(v);
        } else {  // EPI 5: bf16 partial
          ((short*)outp)[(size_t)z * M * N + (size_t)row * N + col] = f2bf(v);
        }
      }
    }
  }
}

// ---- Attention (R8-proven, untouched): 64 q/block, 4 waves, z=4 ----
// Six rounds of evidence: time ~42 us invariant to TLP (R12), LDS traffic
// (R13, worse), HBM fetch (R14, worse). Structural floor for this per-wave
// algorithm; leave untouched.
__global__ __launch_bounds__(256) void attn_kernel(
    const short* __restrict__ Qh, const short* __restrict__ Kh,
    const short* __restrict__ Vt, const int* __restrict__ offs,
    short* __restrict__ Opart, float* __restrict__ Lpart) {
  __shared__ __attribute__((aligned(16))) short Klds[64 * 64];
  __shared__ __attribute__((aligned(16))) short Vlds[64 * 64];
  __shared__ __attribute__((aligned(16))) unsigned int Plds[4][16 * 34];
  int head = blockIdx.y;
  int q0   = blockIdx.x * 64;
  int z    = blockIdx.z;
  int tid  = threadIdx.x;
  int w    = tid >> 6;
  int lane = tid & 63;
  int lcol = lane & 15;
  int h    = lane >> 4;
  int s7   = lcol & 7;
  int o1 = offs[1], o2 = offs[2], o3 = offs[3];

  int qrow = q0 + w * 16 + lcol;
  const short* qb = Qh + ((size_t)head * SEQ + qrow) * HD;
  bf16x8 qf0 = *(const bf16x8*)(qb + h * 8);
  bf16x8 qf1 = *(const bf16x8*)(qb + 32 + h * 8);
  int sq = (qrow >= o1) + (qrow >= o2) + (qrow >= o3);
  U8 qe;
  qe.u[0] = 0; qe.u[1] = 0; qe.u[2] = 0; qe.u[3] = 0;
  if (h == 0) qe.s[sq] = (short)0x3FB9;  // bf16(log2e)

  bf16x8 ones;
#pragma unroll
  for (int i = 0; i < 8; i++) ones[i] = 0x3F80;

  int kb0 = lcol * 64 + ((h ^ s7) * 8);
  int kb1 = lcol * 64 + (((4 + h) ^ s7) * 8);
  int vb0 = kb0, vb1 = kb1;
  int pwb = lcol * 34 + h * 2;
  int prb = lcol * 34 + h * 4;

  int tbeg = z * 512;
  const short* kp0; const short* kp1; const short* vp0; const short* vp1;
  {
    int seg = tid, row = seg >> 3, g = (seg & 7) ^ (row & 7);
    kp0 = Kh + ((size_t)head * SEQ + tbeg + row) * HD + g * 8;
    vp0 = Vt + ((size_t)head * HD + row) * SEQ + tbeg + g * 8;
    seg = 256 + tid; row = seg >> 3; g = (seg & 7) ^ (row & 7);
    kp1 = Kh + ((size_t)head * SEQ + tbeg + row) * HD + g * 8;
    vp1 = Vt + ((size_t)head * HD + row) * SEQ + tbeg + g * 8;
  }

  f32x4 o_acc[4];
#pragma unroll
  for (int nt = 0; nt < 4; nt++) o_acc[nt] = (f32x4){0.f, 0.f, 0.f, 0.f};
  f32x4 acc_l = (f32x4){0.f, 0.f, 0.f, 0.f};

  for (int t0 = 0; t0 < 512; t0 += 64) {
    async_cp16(kp0, Klds + w * 512);          kp0 += 64 * HD;
    async_cp16(kp1, Klds + 2048 + w * 512);   kp1 += 64 * HD;
    async_cp16(vp0, Vlds + w * 512);          vp0 += 64;
    async_cp16(vp1, Vlds + 2048 + w * 512);   vp1 += 64;
    __syncthreads();

#pragma unroll
    for (int n = 0; n < 4; n++) {
      bf16x8 kf0 = *(const bf16x8*)(Klds + n * 1024 + kb0);
      bf16x8 kf1 = *(const bf16x8*)(Klds + n * 1024 + kb1);
      int key = tbeg + t0 + n * 16 + lcol;
      int sk = (key >= o1) + (key >= o2) + (key >= o3);
      U8 ke;
      ke.u[0] = (h == 0) ? ((sk == 0) ? 0x00003F80u : (sk == 1) ? 0x3F800000u : 0u) : 0u;
      ke.u[1] = (h == 0) ? ((sk == 2) ? 0x00003F80u : (sk == 3) ? 0x3F800000u : 0u) : 0u;
      ke.u[2] = 0; ke.u[3] = 0;

      f32x4 sacc = (f32x4){0.f, 0.f, 0.f, 0.f};
      sacc = __builtin_amdgcn_mfma_f32_16x16x32_bf16(kf0, qf0, sacc, 0, 0, 0);
      sacc = __builtin_amdgcn_mfma_f32_16x16x32_bf16(kf1, qf1, sacc, 0, 0, 0);
      sacc = __builtin_amdgcn_mfma_f32_16x16x32_bf16(ke.v, qe.v, sacc, 0, 0, 0);

      float p0 = fast_exp2(sacc[0]);
      float p1 = fast_exp2(sacc[1]);
      float p2 = fast_exp2(sacc[2]);
      float p3 = fast_exp2(sacc[3]);
      uint2 pw;
      pw.x = __builtin_amdgcn_perm(__float_as_uint(p1), __float_as_uint(p0), 0x07060302);
      pw.y = __builtin_amdgcn_perm(__float_as_uint(p3), __float_as_uint(p2), 0x07060302);
      *(uint2*)&Plds[w][pwb + n * 8] = pw;
    }

#pragma unroll
    for (int kc = 0; kc < 2; kc++) {
      uint2 a = *(const uint2*)&Plds[w][prb + kc * 16];
      uint2 b = *(const uint2*)&Plds[w][prb + kc * 16 + 2];
      U8 pu;
      pu.u[0] = a.x; pu.u[1] = a.y; pu.u[2] = b.x; pu.u[3] = b.y;
      int vb = kc ? vb1 : vb0;
#pragma unroll
      for (int nt = 0; nt < 4; nt++) {
        bf16x8 vf = *(const bf16x8*)(Vlds + nt * 1024 + vb);
        o_acc[nt] = __builtin_amdgcn_mfma_f32_16x16x32_bf16(vf, pu.v, o_acc[nt], 0, 0, 0);
      }
      acc_l = __builtin_amdgcn_mfma_f32_16x16x32_bf16(ones, pu.v, acc_l, 0, 0, 0);
    }
    __syncthreads();
  }

  short* op = Opart + ((size_t)z * SEQ + qrow) * HID + head * HD + h * 4;
#pragma unroll
  for (int nt = 0; nt < 4; nt++) {
    uint2 ua;
    ua.x = pkbf(o_acc[nt][0], o_acc[nt][1]);
    ua.y = pkbf(o_acc[nt][2], o_acc[nt][3]);
    *(uint2*)(op + nt * 16) = ua;
  }
  if (lane < 16)
    Lpart[((size_t)z * NH + head) * SEQ + qrow] = acc_l[0];
}

// ---- merge 4 bf16 z-partials, normalize by sum(l), out bf16 ----
__global__ __launch_bounds__(256) void attn_merge_kernel(
    const short* __restrict__ Opart, const float* __restrict__ Lpart,
    short* __restrict__ attn) {
  int i = blockIdx.x * blockDim.x + threadIdx.x;
  int col4 = i & 255;
  int row  = i >> 8;
  int head = col4 >> 4;
  float acc0 = 0.f, acc1 = 0.f, acc2 = 0.f, acc3 = 0.f, l = 0.f;
#pragma unroll
  for (int zz = 0; zz < 4; zz++) {
    uint2 p = ((const uint2*)(Opart + (size_t)zz * SEQ * HID))[i];
    acc0 += bf2f_lo(p.x); acc1 += bf2f_hi(p.x);
    acc2 += bf2f_lo(p.y); acc3 += bf2f_hi(p.y);
    l += Lpart[((size_t)zz * NH + head) * SEQ + row];
  }
  float rl = fast_rcp(l);
  uint2 o;
  o.x = pkbf(acc0 * rl, acc1 * rl);
  o.y = pkbf(acc2 * rl, acc3 * rl);
  ((uint2*)attn)[i] = o;
}

// ------- split-K bf16-partial merge + bias + residual + LayerNorm -------
__global__ __launch_bounds__(256) void merge_ln_kernel(
    const short* __restrict__ part, const float* __restrict__ bias,
    const float* __restrict__ resid, const float* __restrict__ w,
    const float* __restrict__ b, float* __restrict__ x1, short* __restrict__ h1) {
  int row = blockIdx.x;
  int tid = threadIdx.x;
  size_t idx = (size_t)row * HID / 4 + tid;
  float4 v = {0.f, 0.f, 0.f, 0.f};
#pragma unroll
  for (int z = 0; z < 4; z++) {
    uint2 p = ((const uint2*)(part + (size_t)z * SEQ * HID))[idx];
    v.x += bf2f_lo(p.x); v.y += bf2f_hi(p.x);
    v.z += bf2f_lo(p.y); v.w += bf2f_hi(p.y);
  }
  float4 bi = ((const float4*)bias)[tid];
  float4 rs4 = ((const float4*)(resid + (size_t)row * HID))[tid];
  v.x += bi.x + rs4.x; v.y += bi.y + rs4.y; v.z += bi.z + rs4.z; v.w += bi.w + rs4.w;
  ((float4*)(x1 + (size_t)row * HID))[tid] = v;
  float s  = v.x + v.y + v.z + v.w;
  float s2 = v.x*v.x + v.y*v.y + v.z*v.z + v.w*v.w;
#pragma unroll
  for (int o = 32; o >= 1; o >>= 1) {
    s  += __shfl_xor(s,  o);
    s2 += __shfl_xor(s2, o);
  }
  __shared__ float red[8];
  int wv = tid >> 6;
  if ((tid & 63) == 0) { red[wv] = s; red[4 + wv] = s2; }
  __syncthreads();
  float ts  = red[0] + red[1] + red[2] + red[3];
  float ts2 = red[4] + red[5] + red[6] + red[7];
  float mean = ts * (1.0f / HID);
  float var  = ts2 * (1.0f / HID) - mean * mean;
  float rsq = rsqrtf(var + 1e-5f);
  float4 wv4 = ((const float4*)w)[tid];
  float4 bv4 = ((const float4*)b)[tid];
  short4 o;
  o.x = f2bf((v.x - mean) * rsq * wv4.x + bv4.x);
  o.y = f2bf((v.y - mean) * rsq * wv4.y + bv4.y);
  o.z = f2bf((v.z - mean) * rsq * wv4.z + bv4.z);
  o.w = f2bf((v.w - mean) * rsq * wv4.w + bv4.w);
  ((short4*)(h1 + (size_t)row * HID))[tid] = o;
}

// ------- split-K bf16-partial merge + bias + residual -> fp32 out -------
__global__ __launch_bounds__(256) void merge_bias_kernel(
    const short* __restrict__ part, const float* __restrict__ bias,
    const float* __restrict__ resid, float* __restrict__ out) {
  int i = blockIdx.x * blockDim.x + threadIdx.x;
  int col4 = i & 255;
  float4 v = {0.f, 0.f, 0.f, 0.f};
#pragma unroll
  for (int z = 0; z < 4; z++) {
    uint2 p = ((const uint2*)(part + (size_t)z * SEQ * HID))[i];
    v.x += bf2f_lo(p.x); v.y += bf2f_hi(p.x);
    v.z += bf2f_lo(p.y); v.w += bf2f_hi(p.y);
  }
  float4 bi = ((const float4*)bias)[col4];
  float4 rs = ((const float4*)resid)[i];
  float4 o;
  o.x = v.x + bi.x + rs.x;
  o.y = v.y + bi.y + rs.y;
  o.z = v.z + bi.z + rs.z;
  o.w = v.w + bi.w + rs.w;
  ((float4*)out)[i] = o;
}

extern "C" void kernel_launch(void* const* d_in, const int* in_sizes, int n_in,
                              void* d_out, int out_size, void* d_ws, size_t ws_size,
                              hipStream_t stream) {
  const float* x      = (const float*)d_in[0];
  const float* ropec  = (const float*)d_in[1];
  const float* ropes  = (const float*)d_in[2];
  const float* n0w    = (const float*)d_in[3];
  const float* n0b    = (const float*)d_in[4];
  const float* n1w    = (const float*)d_in[5];
  const float* n1b    = (const float*)d_in[6];
  const float* wqkv_w = (const float*)d_in[7];
  const float* wqkv_b = (const float*)d_in[8];
  const float* wo_w   = (const float*)d_in[9];
  const float* wo_b   = (const float*)d_in[10];
  const float* up_w   = (const float*)d_in[11];
  const float* up_b   = (const float*)d_in[12];
  const float* down_w = (const float*)d_in[13];
  const float* down_b = (const float*)d_in[14];
  const int*   offs   = (const int*)d_in[15];
  float* out = (float*)d_out;

  char* base = (char*)d_ws;
  // ---- static layout, lifetime-aliased (peak ~88.6 MB) ----
  short* wqkv_bf = (short*)(base + 0);            //  6.3 MB, whole run
  short* wo_bf   = (short*)(base + 6291456);      //  2.1 MB, whole run
  short* up_bf   = (short*)(base + 8388608);      //  8.4 MB, whole run
  short* down_bf = (short*)(base + 16777216);     //  8.4 MB, whole run
  short* h0      = (short*)(base + 25165824);     //  4.2 MB, dead after qkv gemm
  short* qkv_bf  = (short*)(base + 29360128);     // 12.6 MB, dead after ropev
  short* Qh      = (short*)(base + 41943040);     //  4.2 MB, dead after attn
  short* Kh      = (short*)(base + 46137344);     //  4.2 MB, dead after attn
  short* Vt      = (short*)(base + 50331648);     //  4.2 MB, dead after attn
  short* Opart   = (short*)(base + 54525952);     // 16.8 MB, dead after attn_merge
  float* Lpart   = (float*)(base + 71303168);     //  0.5 MB
  short* attn    = (short*)(base + 71827456);     //  4.2 MB, dead after wo gemm
  float* x1      = (float*)(base + 76021760);     //  8.4 MB, live to end
  short* h1      = (short*)(base + 84410368);     //  4.2 MB, dead after up gemm
  short* wopart  = (short*)(base + 25165824);     // 16.8 MB -> 41.9 MB (h0..Vt dead)
  short* u       = (short*)(base + 25165824);     // 16.8 MB -> 41.9 MB
  short* dnpart  = (short*)(base + 41943040);     // 16.8 MB -> 58.7 MB (Qh..Opart dead)

  cvtln_kernel<<<14336, 256, 0, stream>>>(wqkv_w, wo_w, up_w, down_w,
                                          wqkv_bf, wo_bf, up_bf, down_bf,
                                          x, n0w, n0b, h0);
  // qkv: 24x x 16y = 384 blocks; XCD rects 6x x 8y (ncx=4, ncy=2)
  gemm_bt_kernel<3><<<384, 512, 0, stream>>>(h0, wqkv_bf, wqkv_b, nullptr,
                                             qkv_bf, 2048, 3072, 1024, 1024,
                                             6, 8, 4, 2, 1);
  ropev_kernel<<<dim3(32, 16), 256, 0, stream>>>(qkv_bf, ropec, ropes, Qh, Kh, Vt);
  attn_kernel<<<dim3(32, 16, 4), 256, 0, stream>>>(Qh, Kh, Vt, offs, Opart, Lpart);
  attn_merge_kernel<<<2048, 256, 0, stream>>>(Opart, Lpart, attn);
  // wo: 8x x 16y x 4z = 512 blocks; XCD rects 8x x 8y x 1z (ncx=1, ncy=2)
  gemm_bt_kernel<5><<<512, 512, 0, stream>>>(attn, wo_bf, nullptr, nullptr,
                                             wopart, 2048, 1024, 256, 1024,
                                             8, 8, 1, 2, 1);
  merge_ln_kernel<<<2048, 256, 0, stream>>>(wopart, wo_b, x, n1w, n1b, x1, h1);
  // up: 32x x 16y = 512 blocks; XCD rects 8x x 8y (ncx=4, ncy=2)
  gemm_bt_kernel<2><<<512, 512, 0, stream>>>(h1, up_bf, up_b, nullptr,
                                             u, 2048, 4096, 1024, 1024,
                                             8, 8, 4, 2, 1);
  // down: 8x x 16y x 4z = 512 blocks; XCD rects 8x x 8y x 1z
  gemm_bt_kernel<5><<<512, 512, 0, stream>>>(u, down_bf, nullptr, nullptr,
                                             dnpart, 2048, 1024, 1024, 4096,
                                             8, 8, 1, 2, 1);
  merge_bias_kernel<<<2048, 256, 0, stream>>>(dnpart, down_b, x1, out);
}